// Round 9
// baseline (13222.929 us; speedup 1.0000x reference)
//
#include <hip/hip_runtime.h>

// CustomLSTM — Round 9: faithful f32 LSTM with FLOAT32 output (the r8 bug was
// output dtype: reference outputs are f32 -> d_out is float*, not bf16).
// Structure: per-timestep two kernels, stream-ordered (no cross-WG sync).
//   step_gemm: P[kb][b][col] partial gate sums (h@V k-split 32-wide; x@U
//              folded into kb 0..15)
//   step_cell: gates = b + sum_kb P -> cell update; h,c live in f32 ws bufs.
// Outputs: h_last f32 at out[0:32768], hidden_seq f32 at out[32768+...].
//
// ws layout (17.1 MB): P 16,777,216 | hbuf 131,072 | cbuf 131,072

#define HID 1024
#define BS 32
#define TSTEPS 512
#define WS_NEEDED (16777216 + 131072 + 131072)

__device__ __forceinline__ float sigm(float v) {
  v = fminf(fmaxf(v, -30.f), 30.f);
  return 1.f / (1.f + __expf(-v));
}
__device__ __forceinline__ float tanh_(float v) {
  v = fminf(fmaxf(v, -15.f), 15.f);
  float e = __expf(-2.f * v);
  return (1.f - e) / (1.f + e);
}

// grid (kb=32, cb=16), block 256. Thread owns gate-column `col`, accumulates
// 32 batches over a 32-wide k-slice of h@V (kb<16 also covers x@U).
__global__ __launch_bounds__(256) void r9_step_gemm(
    const float* __restrict__ x, const float* __restrict__ hbuf,
    const float* __restrict__ Vf, const float* __restrict__ Vi,
    const float* __restrict__ Vo, const float* __restrict__ Vg,
    const float* __restrict__ Uf, const float* __restrict__ Ui,
    const float* __restrict__ Uo, const float* __restrict__ Ug,
    float* __restrict__ P, int t) {
  const int kb = blockIdx.x;
  const int cb = blockIdx.y;
  const int tidx = threadIdx.x;
  const int gate = cb >> 2;
  const int j = (cb & 3) * 256 + tidx;
  const int col = cb * 256 + tidx;
  const float* V_ = (gate == 0) ? Vf : (gate == 1) ? Vi : (gate == 2) ? Vo : Vg;
  const float* U_ = (gate == 0) ? Uf : (gate == 1) ? Ui : (gate == 2) ? Uo : Ug;

  __shared__ float hs[BS][32];
  __shared__ float xs2[BS][32];
  {
    int idx = tidx * 4;
#pragma unroll
    for (int i = 0; i < 4; ++i, ++idx) {
      int b = idx >> 5, u = idx & 31;
      hs[b][u] = hbuf[b * HID + kb * 32 + u];
      if (kb < 16) xs2[b][u] = x[((size_t)b * TSTEPS + t) * 512 + kb * 32 + u];
    }
  }
  __syncthreads();

  float acc[BS];
#pragma unroll
  for (int b = 0; b < BS; ++b) acc[b] = 0.f;

  const float* vp = V_ + (size_t)(kb * 32) * HID + j;
#pragma unroll 4
  for (int k = 0; k < 32; ++k) {
    float vv = vp[(size_t)k * HID];
#pragma unroll
    for (int b = 0; b < BS; ++b) acc[b] += hs[b][k] * vv;
  }
  if (kb < 16) {
    const float* up = U_ + (size_t)(kb * 32) * HID + j;
#pragma unroll 4
    for (int k = 0; k < 32; ++k) {
      float uv = up[(size_t)k * HID];
#pragma unroll
      for (int b = 0; b < BS; ++b) acc[b] += xs2[b][k] * uv;
    }
  }

  float* pp = P + (size_t)kb * BS * 4096 + col;
#pragma unroll
  for (int b = 0; b < BS; ++b) pp[(size_t)b * 4096] = acc[b];
}

// 128 blocks x 256 threads = 32 b x 1024 j.
__global__ __launch_bounds__(256) void r9_step_cell(
    const float* __restrict__ P,
    const float* __restrict__ bfv, const float* __restrict__ biv,
    const float* __restrict__ bov, const float* __restrict__ bgv,
    float* __restrict__ hbuf, float* __restrict__ cbuf,
    float* __restrict__ out, int t) {
  const int idx = blockIdx.x * 256 + threadIdx.x;
  const int b = idx >> 10, j = idx & 1023;
  float gf = bfv[j], gi = biv[j], go = bov[j], gg = bgv[j];
  const float* pb = P + (size_t)b * 4096;
#pragma unroll 8
  for (int kb = 0; kb < 32; ++kb) {
    const float* pk = pb + (size_t)kb * BS * 4096;
    gf += pk[j];
    gi += pk[1024 + j];
    go += pk[2048 + j];
    gg += pk[3072 + j];
  }
  float fs = sigm(gf), is = sigm(gi), os = sigm(go), gt = tanh_(gg);
  float c = fs * cbuf[idx] + is * gt;
  cbuf[idx] = c;
  float h = os * tanh_(c);
  hbuf[idx] = h;
  // FLOAT32 output stores (the round-9 fix)
  out[32768 + ((size_t)b * TSTEPS + t) * HID + j] = h;
  if (t == TSTEPS - 1) out[(size_t)b * HID + j] = h;
}

__global__ void r9_sentinel(float* out, float v) {
  out[blockIdx.x * 256 + threadIdx.x] = v;
}

extern "C" void kernel_launch(void* const* d_in, const int* in_sizes, int n_in,
                              void* d_out, int out_size, void* d_ws, size_t ws_size,
                              hipStream_t stream) {
  const float *x, *Uf, *Vf, *bf, *Ui, *Vi, *bi, *Uo, *Vo, *bo, *Ug, *Vg, *bg;
  float* out = (float*)d_out;

  bool okA = (n_in == 13) && in_sizes[0] == 8388608 && in_sizes[1] == 524288 &&
             in_sizes[2] == 1048576 && in_sizes[3] == 1024 &&
             in_sizes[4] == 524288 && in_sizes[7] == 524288 &&
             in_sizes[10] == 524288 && in_sizes[12] == 1024;
  bool okB = (n_in == 13) && in_sizes[0] == 524288 && in_sizes[1] == 524288 &&
             in_sizes[2] == 524288 && in_sizes[3] == 524288 &&
             in_sizes[4] == 1048576 && in_sizes[7] == 1048576 &&
             in_sizes[8] == 1024 && in_sizes[11] == 1024 &&
             in_sizes[12] == 8388608;

  if (okA) {
    // documented setup_inputs() dict order: x, (U,V,b) x {f,i,o,g}
    x = (const float*)d_in[0];
    Uf = (const float*)d_in[1];  Vf = (const float*)d_in[2];  bf = (const float*)d_in[3];
    Ui = (const float*)d_in[4];  Vi = (const float*)d_in[5];  bi = (const float*)d_in[6];
    Uo = (const float*)d_in[7];  Vo = (const float*)d_in[8];  bo = (const float*)d_in[9];
    Ug = (const float*)d_in[10]; Vg = (const float*)d_in[11]; bg = (const float*)d_in[12];
  } else if (okB) {
    // sorted-key order: U_f,U_g,U_i,U_o, V_f,V_g,V_i,V_o, b_f,b_g,b_i,b_o, x
    Uf = (const float*)d_in[0];  Ug = (const float*)d_in[1];
    Ui = (const float*)d_in[2];  Uo = (const float*)d_in[3];
    Vf = (const float*)d_in[4];  Vg = (const float*)d_in[5];
    Vi = (const float*)d_in[6];  Vo = (const float*)d_in[7];
    bf = (const float*)d_in[8];  bg = (const float*)d_in[9];
    bi = (const float*)d_in[10]; bo = (const float*)d_in[11];
    x = (const float*)d_in[12];
  } else {
    r9_sentinel<<<128, 256, 0, stream>>>(out, 3000.0f);  // unknown input pattern
    return;
  }

  if (ws_size < (size_t)WS_NEEDED) {
    r9_sentinel<<<128, 256, 0, stream>>>(out, 2000.0f);  // workspace too small
    return;
  }

  char* ws = (char*)d_ws;
  float* P = (float*)ws;
  float* hbuf = (float*)(ws + 16777216);
  float* cbuf = (float*)(ws + 16908288);

  (void)hipMemsetAsync(hbuf, 0, 131072, stream);
  (void)hipMemsetAsync(cbuf, 0, 131072, stream);
  for (int t = 0; t < TSTEPS; ++t) {
    r9_step_gemm<<<dim3(32, 16), 256, 0, stream>>>(x, hbuf, Vf, Vi, Vo, Vg, Uf, Ui,
                                                   Uo, Ug, P, t);
    r9_step_cell<<<128, 256, 0, stream>>>(P, bf, bi, bo, bg, hbuf, cbuf, out, t);
  }
}

// Round 10
// 7968.793 us; speedup vs baseline: 1.6593x; 1.6593x over previous
//
#include <hip/hip_runtime.h>

// CustomLSTM — Round 10: persistent split-precision MFMA kernel, f32 output.
// (r5 machinery + r9's interface fix; sentinels removed; r9 path kept as
//  ws-size fallback.)
//
// Fast-path ws layout (57 MB):
//   0         flags   4096
//   65536     hfH     262144      (4-slot ring, bf16 A-frag hi)
//   327680    hfL     262144      (lo plane)
//   1048576   vfragH  8388608     | 9437184  vfragL 8388608
//   17825792  ufragH  4194304     | 22020096 ufragL 4194304
//   26214400  xfragH 16777216     | 42991616 xfragL 16777216  (end 59768832)

typedef __bf16 bf16x8 __attribute__((ext_vector_type(8)));
typedef float f32x16 __attribute__((ext_vector_type(16)));

#define NWG 64
#define T_STEPS 512
#define HID 1024
#define BS 32
#define WS_FAST 59768832
#define WS_SLOW (16777216 + 131072 + 131072)

__device__ __forceinline__ unsigned short f2bf(float f) {
  unsigned int u = __float_as_uint(f);
  u = (u + 0x7FFFu + ((u >> 16) & 1u)) >> 16;
  return (unsigned short)u;
}
__device__ __forceinline__ float b2f(unsigned short s) {
  return __uint_as_float(((unsigned int)s) << 16);
}
__device__ __forceinline__ float sigm(float v) {
  v = fminf(fmaxf(v, -30.f), 30.f);
  return 1.f / (1.f + __expf(-v));
}
__device__ __forceinline__ float tanh_(float v) {
  v = fminf(fmaxf(v, -15.f), 15.f);
  float e = __expf(-2.f * v);
  return (1.f - e) / (1.f + e);
}

// ---- x -> bf16 A-frags hi+lo: [t][kt 0..31][lane][4 dwords] ----
// A-frag map (32x32x16): row b = lane&31, k = 8*(lane>>5) + 2r + {0,1}
__global__ void cvt_x_kernel(const float* __restrict__ x,
                             unsigned int* __restrict__ xfH,
                             unsigned int* __restrict__ xfL) {
  const int t = blockIdx.x;
  const int tid = threadIdx.x;
  __shared__ float xs[32 * 512];
  {
    const int b = tid >> 3;
    const int k0 = (tid & 7) * 64;
    const float* src = x + ((size_t)(b * 512 + t)) * 512 + k0;
    for (int i = 0; i < 64; i += 4) {
      float4 v = *reinterpret_cast<const float4*>(src + i);
      xs[b * 512 + k0 + i + 0] = v.x;
      xs[b * 512 + k0 + i + 1] = v.y;
      xs[b * 512 + k0 + i + 2] = v.z;
      xs[b * 512 + k0 + i + 3] = v.w;
    }
  }
  __syncthreads();
  unsigned int* dH = xfH + (size_t)t * 8192;
  unsigned int* dL = xfL + (size_t)t * 8192;
  for (int i = 0; i < 32; ++i) {
    int idx = i * 256 + tid;
    int kt = idx >> 8;
    int pos = idx & 255;
    int lane = pos >> 2;
    int r = pos & 3;
    int kk = 8 * (lane >> 5) + 2 * r;
    int b2 = lane & 31;
    float f0 = xs[b2 * 512 + kt * 16 + kk];
    float f1 = xs[b2 * 512 + kt * 16 + kk + 1];
    unsigned short h0 = f2bf(f0), h1 = f2bf(f1);
    unsigned short l0 = f2bf(f0 - b2f(h0)), l1 = f2bf(f1 - b2f(h1));
    dH[idx] = (unsigned int)h0 | ((unsigned int)h1 << 16);
    dL[idx] = (unsigned int)l0 | ((unsigned int)l1 << 16);
  }
}

// ---- U,V -> B-frags hi+lo. V: kt 0..63. U: kt 64..95 ----
__global__ void cvt_uv_kernel(const float* Uf, const float* Vf,
                              const float* Ui, const float* Vi,
                              const float* Uo, const float* Vo,
                              const float* Ug, const float* Vg,
                              unsigned int* __restrict__ vfH,
                              unsigned int* __restrict__ vfL,
                              unsigned int* __restrict__ ufH,
                              unsigned int* __restrict__ ufL) {
  int blk = blockIdx.x;  // 64*2*96
  int kt = blk % 96;
  int nt = (blk / 96) & 1;
  int wg = blk / 192;
  int lane = threadIdx.x;
  int col32 = lane & 31;
  int c64 = nt * 32 + col32;
  int gate = c64 >> 4;
  int jg = wg * 16 + (c64 & 15);
  const float* V_ = (gate == 0) ? Vf : (gate == 1) ? Vi : (gate == 2) ? Vo : Vg;
  const float* U_ = (gate == 0) ? Uf : (gate == 1) ? Ui : (gate == 2) ? Uo : Ug;
  for (int r = 0; r < 4; ++r) {
    int kk = 8 * (lane >> 5) + 2 * r;
    if (kt < 64) {
      int K = kt * 16 + kk;
      float f0 = V_[(size_t)K * HID + jg];
      float f1 = V_[(size_t)(K + 1) * HID + jg];
      unsigned short h0 = f2bf(f0), h1 = f2bf(f1);
      unsigned short l0 = f2bf(f0 - b2f(h0)), l1 = f2bf(f1 - b2f(h1));
      size_t idx = ((size_t)(wg * 2 + nt) * 64 + kt) * 256 + lane * 4 + r;
      vfH[idx] = (unsigned int)h0 | ((unsigned int)h1 << 16);
      vfL[idx] = (unsigned int)l0 | ((unsigned int)l1 << 16);
    } else {
      int K = (kt - 64) * 16 + kk;
      float f0 = U_[(size_t)K * HID + jg];
      float f1 = U_[(size_t)(K + 1) * HID + jg];
      unsigned short h0 = f2bf(f0), h1 = f2bf(f1);
      unsigned short l0 = f2bf(f0 - b2f(h0)), l1 = f2bf(f1 - b2f(h1));
      size_t idx = ((size_t)(wg * 2 + nt) * 32 + (kt - 64)) * 256 + lane * 4 + r;
      ufH[idx] = (unsigned int)h0 | ((unsigned int)h1 << 16);
      ufL[idx] = (unsigned int)l0 | ((unsigned int)l1 << 16);
    }
  }
}

__device__ __forceinline__ int gidx(int nt, int w, int row, int col) {
  return ((nt * 8 + w) * 32 + row) * 32 + (col ^ row);
}

// ---- persistent recurrent kernel: 64 WGs x 512 threads (8 waves) ----
__global__ __launch_bounds__(512, 2) void lstm_main_kernel(
    const unsigned short* __restrict__ ufragH,
    const unsigned short* __restrict__ ufragL,
    const unsigned short* __restrict__ vfragH,
    const unsigned short* __restrict__ vfragL,
    const unsigned short* __restrict__ xfragH,
    const unsigned short* __restrict__ xfragL,
    unsigned int* hfH, unsigned int* hfL, unsigned int* flags,
    const float* __restrict__ bfv, const float* __restrict__ biv,
    const float* __restrict__ bov, const float* __restrict__ bgv,
    float* __restrict__ out) {
  __shared__ unsigned short ldsU[2 * 32 * 512];  // 64 KB: U hi frags
  __shared__ float gbuf[2 * 8 * 32 * 32];        // 64 KB, XOR-swizzled
  __shared__ float hcell[32][17];

  const int wg = blockIdx.x;
  const int tid = threadIdx.x;
  const int lane = tid & 63;
  const int w = tid >> 6;

  {
    const bf16x8* src = reinterpret_cast<const bf16x8*>(ufragH + (size_t)wg * 32768);
    bf16x8* dst = reinterpret_cast<bf16x8*>(ldsU);
    for (int i = 0; i < 8; ++i) dst[i * 512 + tid] = src[i * 512 + tid];
  }
  __syncthreads();
  __builtin_amdgcn_fence(__ATOMIC_ACQUIRE, "agent");  // stale-L2 kill (replays)

  bf16x8 uL[2][4], vH[2][8], vL[2][8];
#pragma unroll
  for (int nt = 0; nt < 2; ++nt) {
    const bf16x8* bl = reinterpret_cast<const bf16x8*>(ufragL + (size_t)wg * 32768) +
                       (size_t)nt * 32 * 64;
#pragma unroll
    for (int p = 0; p < 4; ++p) uL[nt][p] = bl[(w * 4 + p) * 64 + lane];
    const bf16x8* vh =
        reinterpret_cast<const bf16x8*>(vfragH + (size_t)((wg * 2 + nt) * 64) * 512);
    const bf16x8* vl =
        reinterpret_cast<const bf16x8*>(vfragL + (size_t)((wg * 2 + nt) * 64) * 512);
#pragma unroll
    for (int q = 0; q < 8; ++q) {
      vH[nt][q] = vh[(w * 8 + q) * 64 + lane];
      vL[nt][q] = vl[(w * 8 + q) * 64 + lane];
    }
  }

  const int b_ = tid & 31;
  const int jl = tid >> 5;  // 0..15
  const int jg = wg * 16 + jl;
  const float Bf = bfv[jg], Bi = biv[jg], Bo = bov[jg], Bg = bgv[jg];
  float c = 0.f;

#pragma unroll 1
  for (int t = 0; t < T_STEPS; ++t) {
    f32x16 acc0 = {};
    f32x16 acc1 = {};

    // ---- x@U hi+lo (no h dependency: issued before the flag wait) ----
    {
      const bf16x8* axh = reinterpret_cast<const bf16x8*>(xfragH + (size_t)t * 16384);
      const bf16x8* axl = reinterpret_cast<const bf16x8*>(xfragL + (size_t)t * 16384);
      const bf16x8* lu = reinterpret_cast<const bf16x8*>(ldsU);
#pragma unroll
      for (int p = 0; p < 4; ++p) {
        int ktx = w * 4 + p;
        bf16x8 ah = axh[ktx * 64 + lane];
        bf16x8 al = axl[ktx * 64 + lane];
        bf16x8 u0 = lu[ktx * 64 + lane];
        bf16x8 u1 = lu[(32 + ktx) * 64 + lane];
        acc0 = __builtin_amdgcn_mfma_f32_32x32x16_bf16(ah, u0, acc0, 0, 0, 0);
        acc0 = __builtin_amdgcn_mfma_f32_32x32x16_bf16(ah, uL[0][p], acc0, 0, 0, 0);
        acc0 = __builtin_amdgcn_mfma_f32_32x32x16_bf16(al, u0, acc0, 0, 0, 0);
        acc1 = __builtin_amdgcn_mfma_f32_32x32x16_bf16(ah, u1, acc1, 0, 0, 0);
        acc1 = __builtin_amdgcn_mfma_f32_32x32x16_bf16(ah, uL[1][p], acc1, 0, 0, 0);
        acc1 = __builtin_amdgcn_mfma_f32_32x32x16_bf16(al, u1, acc1, 0, 0, 0);
      }
    }

    // ---- wait all h_{t-1}, then 3-term h@V ----
    if (t > 0) {
      if (tid < NWG) {
        while (__hip_atomic_load(&flags[tid * 16], __ATOMIC_RELAXED,
                                 __HIP_MEMORY_SCOPE_AGENT) < (unsigned int)t) {
        }
      }
      __syncthreads();
      __builtin_amdgcn_fence(__ATOMIC_ACQUIRE, "agent");
      const unsigned int* hbH = hfH + (size_t)((t - 1) & 3) * 16384 + lane * 4;
      const unsigned int* hbL = hfL + (size_t)((t - 1) & 3) * 16384 + lane * 4;
#pragma unroll
      for (int half = 0; half < 2; ++half) {
        unsigned int rH[16], rL[16];
#pragma unroll
        for (int q = 0; q < 4; ++q)
#pragma unroll
          for (int d = 0; d < 4; ++d) {
            int qq = half * 4 + q;
            rH[q * 4 + d] = __hip_atomic_load(hbH + (w * 8 + qq) * 256 + d,
                                              __ATOMIC_RELAXED,
                                              __HIP_MEMORY_SCOPE_AGENT);
            rL[q * 4 + d] = __hip_atomic_load(hbL + (w * 8 + qq) * 256 + d,
                                              __ATOMIC_RELAXED,
                                              __HIP_MEMORY_SCOPE_AGENT);
          }
#pragma unroll
        for (int q = 0; q < 4; ++q) {
          int qq = half * 4 + q;
          union { unsigned int u[4]; bf16x8 v; } aH, aL;
#pragma unroll
          for (int d = 0; d < 4; ++d) {
            aH.u[d] = rH[q * 4 + d];
            aL.u[d] = rL[q * 4 + d];
          }
          acc0 = __builtin_amdgcn_mfma_f32_32x32x16_bf16(aH.v, vH[0][qq], acc0, 0, 0, 0);
          acc0 = __builtin_amdgcn_mfma_f32_32x32x16_bf16(aH.v, vL[0][qq], acc0, 0, 0, 0);
          acc0 = __builtin_amdgcn_mfma_f32_32x32x16_bf16(aL.v, vH[0][qq], acc0, 0, 0, 0);
          acc1 = __builtin_amdgcn_mfma_f32_32x32x16_bf16(aH.v, vH[1][qq], acc1, 0, 0, 0);
          acc1 = __builtin_amdgcn_mfma_f32_32x32x16_bf16(aH.v, vL[1][qq], acc1, 0, 0, 0);
          acc1 = __builtin_amdgcn_mfma_f32_32x32x16_bf16(aL.v, vH[1][qq], acc1, 0, 0, 0);
        }
      }
    }

    // ---- write partial C tiles (measured C/D layout), XOR-swizzled ----
    {
      const int colw = lane & 31;
      const int rbase = 4 * (lane >> 5);
#pragma unroll
      for (int r = 0; r < 16; ++r) {
        int row = (r & 3) + 8 * (r >> 2) + rbase;
        gbuf[gidx(0, w, row, colw)] = acc0[r];
        gbuf[gidx(1, w, row, colw)] = acc1[r];
      }
    }
    __syncthreads();

    // ---- cell update (1 hidden unit per thread) ----
    {
      float gf = Bf, gi = Bi, go = Bo, gg = Bg;
#pragma unroll
      for (int ww = 0; ww < 8; ++ww) {
        gf += gbuf[gidx(0, ww, b_, jl)];
        gi += gbuf[gidx(0, ww, b_, 16 + jl)];
        go += gbuf[gidx(1, ww, b_, jl)];
        gg += gbuf[gidx(1, ww, b_, 16 + jl)];
      }
      float fs = sigm(gf), is = sigm(gi), os = sigm(go), gt = tanh_(gg);
      c = fs * c + is * gt;
      hcell[b_][jl] = os * tanh_(c);
    }
    __syncthreads();

    // ---- outputs (f32, coalesced 64B lines) + h publish ----
    {
      const int b2 = tid >> 4, jj = tid & 15;
      float hv = hcell[b2][jj];
      out[32768 + ((size_t)(b2 * T_STEPS + t)) * HID + wg * 16 + jj] = hv;
      if (t == T_STEPS - 1) out[(size_t)b2 * HID + wg * 16 + jj] = hv;
    }
    if (tid < 256) {
      const int b2 = tid >> 3, jp = tid & 7;
      float h0 = hcell[b2][2 * jp], h1 = hcell[b2][2 * jp + 1];
      unsigned short h0h = f2bf(h0), h1h = f2bf(h1);
      unsigned short h0l = f2bf(h0 - b2f(h0h)), h1l = f2bf(h1 - b2f(h1h));
      unsigned int hvH = (unsigned int)h0h | ((unsigned int)h1h << 16);
      unsigned int hvL = (unsigned int)h0l | ((unsigned int)h1l << 16);
      int hw = wg * 256 + (b2 + 32 * (jp >> 2)) * 4 + (jp & 3);
      atomicExch(&hfH[(size_t)(t & 3) * 16384 + hw], hvH);
      atomicExch(&hfL[(size_t)(t & 3) * 16384 + hw], hvL);
    }
    __syncthreads();  // publish drained (vmcnt 0) before flag release
    if (tid == 0) {
      __hip_atomic_store(&flags[wg * 16], (unsigned int)(t + 1), __ATOMIC_RELEASE,
                         __HIP_MEMORY_SCOPE_AGENT);
    }
  }
}

// ================= r9 fallback (proven) =================
__global__ __launch_bounds__(256) void r9_step_gemm(
    const float* __restrict__ x, const float* __restrict__ hbuf,
    const float* __restrict__ Vf, const float* __restrict__ Vi,
    const float* __restrict__ Vo, const float* __restrict__ Vg,
    const float* __restrict__ Uf, const float* __restrict__ Ui,
    const float* __restrict__ Uo, const float* __restrict__ Ug,
    float* __restrict__ P, int t) {
  const int kb = blockIdx.x;
  const int cb = blockIdx.y;
  const int tidx = threadIdx.x;
  const int gate = cb >> 2;
  const int j = (cb & 3) * 256 + tidx;
  const int col = cb * 256 + tidx;
  const float* V_ = (gate == 0) ? Vf : (gate == 1) ? Vi : (gate == 2) ? Vo : Vg;
  const float* U_ = (gate == 0) ? Uf : (gate == 1) ? Ui : (gate == 2) ? Uo : Ug;
  __shared__ float hs[BS][32];
  __shared__ float xs2[BS][32];
  {
    int idx = tidx * 4;
#pragma unroll
    for (int i = 0; i < 4; ++i, ++idx) {
      int b = idx >> 5, u = idx & 31;
      hs[b][u] = hbuf[b * HID + kb * 32 + u];
      if (kb < 16) xs2[b][u] = x[((size_t)b * T_STEPS + t) * 512 + kb * 32 + u];
    }
  }
  __syncthreads();
  float acc[BS];
#pragma unroll
  for (int b = 0; b < BS; ++b) acc[b] = 0.f;
  const float* vp = V_ + (size_t)(kb * 32) * HID + j;
#pragma unroll 4
  for (int k = 0; k < 32; ++k) {
    float vv = vp[(size_t)k * HID];
#pragma unroll
    for (int b = 0; b < BS; ++b) acc[b] += hs[b][k] * vv;
  }
  if (kb < 16) {
    const float* up = U_ + (size_t)(kb * 32) * HID + j;
#pragma unroll 4
    for (int k = 0; k < 32; ++k) {
      float uv = up[(size_t)k * HID];
#pragma unroll
      for (int b = 0; b < BS; ++b) acc[b] += xs2[b][k] * uv;
    }
  }
  float* pp = P + (size_t)kb * BS * 4096 + col;
#pragma unroll
  for (int b = 0; b < BS; ++b) pp[(size_t)b * 4096] = acc[b];
}

__global__ __launch_bounds__(256) void r9_step_cell(
    const float* __restrict__ P,
    const float* __restrict__ bfv, const float* __restrict__ biv,
    const float* __restrict__ bov, const float* __restrict__ bgv,
    float* __restrict__ hbuf, float* __restrict__ cbuf,
    float* __restrict__ out, int t) {
  const int idx = blockIdx.x * 256 + threadIdx.x;
  const int b = idx >> 10, j = idx & 1023;
  float gf = bfv[j], gi = biv[j], go = bov[j], gg = bgv[j];
  const float* pb = P + (size_t)b * 4096;
#pragma unroll 8
  for (int kb = 0; kb < 32; ++kb) {
    const float* pk = pb + (size_t)kb * BS * 4096;
    gf += pk[j];
    gi += pk[1024 + j];
    go += pk[2048 + j];
    gg += pk[3072 + j];
  }
  float fs = sigm(gf), is = sigm(gi), os = sigm(go), gt = tanh_(gg);
  float c = fs * cbuf[idx] + is * gt;
  cbuf[idx] = c;
  float h = os * tanh_(c);
  hbuf[idx] = h;
  out[32768 + ((size_t)b * T_STEPS + t) * HID + j] = h;
  if (t == T_STEPS - 1) out[(size_t)b * HID + j] = h;
}

extern "C" void kernel_launch(void* const* d_in, const int* in_sizes, int n_in,
                              void* d_out, int out_size, void* d_ws, size_t ws_size,
                              hipStream_t stream) {
  const float *x, *Uf, *Vf, *bf, *Ui, *Vi, *bi, *Uo, *Vo, *bo, *Ug, *Vg, *bg;
  float* out = (float*)d_out;

  bool okA = (n_in == 13) && in_sizes[0] == 8388608 && in_sizes[1] == 524288 &&
             in_sizes[2] == 1048576 && in_sizes[3] == 1024 &&
             in_sizes[4] == 524288 && in_sizes[7] == 524288 &&
             in_sizes[10] == 524288 && in_sizes[12] == 1024;
  if (okA) {
    x = (const float*)d_in[0];
    Uf = (const float*)d_in[1];  Vf = (const float*)d_in[2];  bf = (const float*)d_in[3];
    Ui = (const float*)d_in[4];  Vi = (const float*)d_in[5];  bi = (const float*)d_in[6];
    Uo = (const float*)d_in[7];  Vo = (const float*)d_in[8];  bo = (const float*)d_in[9];
    Ug = (const float*)d_in[10]; Vg = (const float*)d_in[11]; bg = (const float*)d_in[12];
  } else {
    // sorted-key order fallback: U_f,U_g,U_i,U_o,V_f,V_g,V_i,V_o,b_f..,x
    Uf = (const float*)d_in[0];  Ug = (const float*)d_in[1];
    Ui = (const float*)d_in[2];  Uo = (const float*)d_in[3];
    Vf = (const float*)d_in[4];  Vg = (const float*)d_in[5];
    Vi = (const float*)d_in[6];  Vo = (const float*)d_in[7];
    bf = (const float*)d_in[8];  bg = (const float*)d_in[9];
    bi = (const float*)d_in[10]; bo = (const float*)d_in[11];
    x = (const float*)d_in[12];
  }

  char* ws = (char*)d_ws;
  if (ws_size >= (size_t)WS_FAST) {
    unsigned int* flags = (unsigned int*)(ws + 0);
    unsigned int* hfH = (unsigned int*)(ws + 65536);
    unsigned int* hfL = (unsigned int*)(ws + 327680);
    unsigned short* vfragH = (unsigned short*)(ws + 1048576);
    unsigned short* vfragL = (unsigned short*)(ws + 9437184);
    unsigned short* ufragH = (unsigned short*)(ws + 17825792);
    unsigned short* ufragL = (unsigned short*)(ws + 22020096);
    unsigned short* xfragH = (unsigned short*)(ws + 26214400);
    unsigned short* xfragL = (unsigned short*)(ws + 42991616);

    (void)hipMemsetAsync(flags, 0, 4096, stream);
    cvt_uv_kernel<<<64 * 2 * 96, 64, 0, stream>>>(
        Uf, Vf, Ui, Vi, Uo, Vo, Ug, Vg, (unsigned int*)vfragH, (unsigned int*)vfragL,
        (unsigned int*)ufragH, (unsigned int*)ufragL);
    cvt_x_kernel<<<512, 256, 0, stream>>>(x, (unsigned int*)xfragH,
                                          (unsigned int*)xfragL);
    lstm_main_kernel<<<NWG, 512, 0, stream>>>(ufragH, ufragL, vfragH, vfragL, xfragH,
                                              xfragL, hfH, hfL, flags, bf, bi, bo,
                                              bg, out);
  } else {
    float* P = (float*)ws;
    float* hbuf = (float*)(ws + 16777216);
    float* cbuf = (float*)(ws + 16908288);
    (void)hipMemsetAsync(hbuf, 0, 131072, stream);
    (void)hipMemsetAsync(cbuf, 0, 131072, stream);
    for (int t = 0; t < T_STEPS; ++t) {
      r9_step_gemm<<<dim3(32, 16), 256, 0, stream>>>(x, hbuf, Vf, Vi, Vo, Vg, Uf, Ui,
                                                     Uo, Ug, P, t);
      r9_step_cell<<<128, 256, 0, stream>>>(P, bf, bi, bo, bg, hbuf, cbuf, out, t);
    }
  }
}

// Round 11
// 6026.262 us; speedup vs baseline: 2.1942x; 1.3223x over previous
//
#include <hip/hip_runtime.h>

// CustomLSTM — Round 11: r10 minus per-step coherence overkill.
//   - NO per-step acquire fence (buffer_inv x512 removed); one at kernel start.
//   - flag store RELAXED (release's L2-writeback x512 removed); ordering is
//     guaranteed by __syncthreads' vmcnt(0) drain of the sc1 h-publishes.
//   - h publish: plain sc1 store (__hip_atomic_store RELAXED) not atomicExch.
//   - h@V loads: ONE 64-dword batch (single L3 latency exposure).
//   - out stores nontemporal (never re-read; don't dirty L2).
// Ring-slot safety: flag wait bounds WG skew to 1 step; concurrent window is
// {t, t+1} writes vs {t-1, t} reads -> 4-slot ring has no overlap.
//
// Fast-path ws layout (57 MB):
//   0         flags   4096
//   65536     hfH     262144      (4-slot ring, bf16 A-frag hi)
//   327680    hfL     262144      (lo plane)
//   1048576   vfragH  8388608     | 9437184  vfragL 8388608
//   17825792  ufragH  4194304     | 22020096 ufragL 4194304
//   26214400  xfragH 16777216     | 42991616 xfragL 16777216  (end 59768832)

typedef __bf16 bf16x8 __attribute__((ext_vector_type(8)));
typedef float f32x16 __attribute__((ext_vector_type(16)));

#define NWG 64
#define T_STEPS 512
#define HID 1024
#define BS 32
#define WS_FAST 59768832

__device__ __forceinline__ unsigned short f2bf(float f) {
  unsigned int u = __float_as_uint(f);
  u = (u + 0x7FFFu + ((u >> 16) & 1u)) >> 16;
  return (unsigned short)u;
}
__device__ __forceinline__ float b2f(unsigned short s) {
  return __uint_as_float(((unsigned int)s) << 16);
}
__device__ __forceinline__ float sigm(float v) {
  v = fminf(fmaxf(v, -30.f), 30.f);
  return 1.f / (1.f + __expf(-v));
}
__device__ __forceinline__ float tanh_(float v) {
  v = fminf(fmaxf(v, -15.f), 15.f);
  float e = __expf(-2.f * v);
  return (1.f - e) / (1.f + e);
}

// ---- x -> bf16 A-frags hi+lo: [t][kt 0..31][lane][4 dwords] ----
// A-frag map (32x32x16): row b = lane&31, k = 8*(lane>>5) + 2r + {0,1}
__global__ void cvt_x_kernel(const float* __restrict__ x,
                             unsigned int* __restrict__ xfH,
                             unsigned int* __restrict__ xfL) {
  const int t = blockIdx.x;
  const int tid = threadIdx.x;
  __shared__ float xs[32 * 512];
  {
    const int b = tid >> 3;
    const int k0 = (tid & 7) * 64;
    const float* src = x + ((size_t)(b * 512 + t)) * 512 + k0;
    for (int i = 0; i < 64; i += 4) {
      float4 v = *reinterpret_cast<const float4*>(src + i);
      xs[b * 512 + k0 + i + 0] = v.x;
      xs[b * 512 + k0 + i + 1] = v.y;
      xs[b * 512 + k0 + i + 2] = v.z;
      xs[b * 512 + k0 + i + 3] = v.w;
    }
  }
  __syncthreads();
  unsigned int* dH = xfH + (size_t)t * 8192;
  unsigned int* dL = xfL + (size_t)t * 8192;
  for (int i = 0; i < 32; ++i) {
    int idx = i * 256 + tid;
    int kt = idx >> 8;
    int pos = idx & 255;
    int lane = pos >> 2;
    int r = pos & 3;
    int kk = 8 * (lane >> 5) + 2 * r;
    int b2 = lane & 31;
    float f0 = xs[b2 * 512 + kt * 16 + kk];
    float f1 = xs[b2 * 512 + kt * 16 + kk + 1];
    unsigned short h0 = f2bf(f0), h1 = f2bf(f1);
    unsigned short l0 = f2bf(f0 - b2f(h0)), l1 = f2bf(f1 - b2f(h1));
    dH[idx] = (unsigned int)h0 | ((unsigned int)h1 << 16);
    dL[idx] = (unsigned int)l0 | ((unsigned int)l1 << 16);
  }
}

// ---- U,V -> B-frags hi+lo. V: kt 0..63. U: kt 64..95 ----
__global__ void cvt_uv_kernel(const float* Uf, const float* Vf,
                              const float* Ui, const float* Vi,
                              const float* Uo, const float* Vo,
                              const float* Ug, const float* Vg,
                              unsigned int* __restrict__ vfH,
                              unsigned int* __restrict__ vfL,
                              unsigned int* __restrict__ ufH,
                              unsigned int* __restrict__ ufL) {
  int blk = blockIdx.x;  // 64*2*96
  int kt = blk % 96;
  int nt = (blk / 96) & 1;
  int wg = blk / 192;
  int lane = threadIdx.x;
  int col32 = lane & 31;
  int c64 = nt * 32 + col32;
  int gate = c64 >> 4;
  int jg = wg * 16 + (c64 & 15);
  const float* V_ = (gate == 0) ? Vf : (gate == 1) ? Vi : (gate == 2) ? Vo : Vg;
  const float* U_ = (gate == 0) ? Uf : (gate == 1) ? Ui : (gate == 2) ? Uo : Ug;
  for (int r = 0; r < 4; ++r) {
    int kk = 8 * (lane >> 5) + 2 * r;
    if (kt < 64) {
      int K = kt * 16 + kk;
      float f0 = V_[(size_t)K * HID + jg];
      float f1 = V_[(size_t)(K + 1) * HID + jg];
      unsigned short h0 = f2bf(f0), h1 = f2bf(f1);
      unsigned short l0 = f2bf(f0 - b2f(h0)), l1 = f2bf(f1 - b2f(h1));
      size_t idx = ((size_t)(wg * 2 + nt) * 64 + kt) * 256 + lane * 4 + r;
      vfH[idx] = (unsigned int)h0 | ((unsigned int)h1 << 16);
      vfL[idx] = (unsigned int)l0 | ((unsigned int)l1 << 16);
    } else {
      int K = (kt - 64) * 16 + kk;
      float f0 = U_[(size_t)K * HID + jg];
      float f1 = U_[(size_t)(K + 1) * HID + jg];
      unsigned short h0 = f2bf(f0), h1 = f2bf(f1);
      unsigned short l0 = f2bf(f0 - b2f(h0)), l1 = f2bf(f1 - b2f(h1));
      size_t idx = ((size_t)(wg * 2 + nt) * 32 + (kt - 64)) * 256 + lane * 4 + r;
      ufH[idx] = (unsigned int)h0 | ((unsigned int)h1 << 16);
      ufL[idx] = (unsigned int)l0 | ((unsigned int)l1 << 16);
    }
  }
}

__device__ __forceinline__ int gidx(int nt, int w, int row, int col) {
  return ((nt * 8 + w) * 32 + row) * 32 + (col ^ row);
}

// ---- persistent recurrent kernel: 64 WGs x 512 threads (8 waves) ----
__global__ __launch_bounds__(512, 2) void lstm_main_kernel(
    const unsigned short* __restrict__ ufragH,
    const unsigned short* __restrict__ ufragL,
    const unsigned short* __restrict__ vfragH,
    const unsigned short* __restrict__ vfragL,
    const unsigned short* __restrict__ xfragH,
    const unsigned short* __restrict__ xfragL,
    unsigned int* hfH, unsigned int* hfL, unsigned int* flags,
    const float* __restrict__ bfv, const float* __restrict__ biv,
    const float* __restrict__ bov, const float* __restrict__ bgv,
    float* __restrict__ out) {
  __shared__ unsigned short ldsU[2 * 32 * 512];  // 64 KB: U hi frags
  __shared__ float gbuf[2 * 8 * 32 * 32];        // 64 KB, XOR-swizzled
  __shared__ float hcell[32][17];

  const int wg = blockIdx.x;
  const int tid = threadIdx.x;
  const int lane = tid & 63;
  const int w = tid >> 6;

  {
    const bf16x8* src = reinterpret_cast<const bf16x8*>(ufragH + (size_t)wg * 32768);
    bf16x8* dst = reinterpret_cast<bf16x8*>(ldsU);
    for (int i = 0; i < 8; ++i) dst[i * 512 + tid] = src[i * 512 + tid];
  }
  __syncthreads();
  __builtin_amdgcn_fence(__ATOMIC_ACQUIRE, "agent");  // once: replay-stale kill

  bf16x8 uL[2][4], vH[2][8], vL[2][8];
#pragma unroll
  for (int nt = 0; nt < 2; ++nt) {
    const bf16x8* bl = reinterpret_cast<const bf16x8*>(ufragL + (size_t)wg * 32768) +
                       (size_t)nt * 32 * 64;
#pragma unroll
    for (int p = 0; p < 4; ++p) uL[nt][p] = bl[(w * 4 + p) * 64 + lane];
    const bf16x8* vh =
        reinterpret_cast<const bf16x8*>(vfragH + (size_t)((wg * 2 + nt) * 64) * 512);
    const bf16x8* vl =
        reinterpret_cast<const bf16x8*>(vfragL + (size_t)((wg * 2 + nt) * 64) * 512);
#pragma unroll
    for (int q = 0; q < 8; ++q) {
      vH[nt][q] = vh[(w * 8 + q) * 64 + lane];
      vL[nt][q] = vl[(w * 8 + q) * 64 + lane];
    }
  }

  const int b_ = tid & 31;
  const int jl = tid >> 5;  // 0..15
  const int jg = wg * 16 + jl;
  const float Bf = bfv[jg], Bi = biv[jg], Bo = bov[jg], Bg = bgv[jg];
  float c = 0.f;

#pragma unroll 1
  for (int t = 0; t < T_STEPS; ++t) {
    f32x16 acc0 = {};
    f32x16 acc1 = {};

    // ---- x@U hi+lo (no h dependency: issued before the flag wait) ----
    {
      const bf16x8* axh = reinterpret_cast<const bf16x8*>(xfragH + (size_t)t * 16384);
      const bf16x8* axl = reinterpret_cast<const bf16x8*>(xfragL + (size_t)t * 16384);
      const bf16x8* lu = reinterpret_cast<const bf16x8*>(ldsU);
#pragma unroll
      for (int p = 0; p < 4; ++p) {
        int ktx = w * 4 + p;
        bf16x8 ah = axh[ktx * 64 + lane];
        bf16x8 al = axl[ktx * 64 + lane];
        bf16x8 u0 = lu[ktx * 64 + lane];
        bf16x8 u1 = lu[(32 + ktx) * 64 + lane];
        acc0 = __builtin_amdgcn_mfma_f32_32x32x16_bf16(ah, u0, acc0, 0, 0, 0);
        acc0 = __builtin_amdgcn_mfma_f32_32x32x16_bf16(ah, uL[0][p], acc0, 0, 0, 0);
        acc0 = __builtin_amdgcn_mfma_f32_32x32x16_bf16(al, u0, acc0, 0, 0, 0);
        acc1 = __builtin_amdgcn_mfma_f32_32x32x16_bf16(ah, u1, acc1, 0, 0, 0);
        acc1 = __builtin_amdgcn_mfma_f32_32x32x16_bf16(ah, uL[1][p], acc1, 0, 0, 0);
        acc1 = __builtin_amdgcn_mfma_f32_32x32x16_bf16(al, u1, acc1, 0, 0, 0);
      }
    }

    // ---- wait all h_{t-1}, then 3-term h@V ----
    if (t > 0) {
      if (tid < NWG) {
        while (__hip_atomic_load(&flags[tid * 16], __ATOMIC_RELAXED,
                                 __HIP_MEMORY_SCOPE_AGENT) < (unsigned int)t) {
        }
      }
      __syncthreads();
      // (no fence: h reads below are sc1 L2-bypass loads from the L3
      //  coherence point; publishes completed before the flag was set)
      const unsigned int* hbH = hfH + (size_t)((t - 1) & 3) * 16384 + lane * 4;
      const unsigned int* hbL = hfL + (size_t)((t - 1) & 3) * 16384 + lane * 4;
      unsigned int rH[32], rL[32];
      // ONE load batch: single L3 latency exposure for all 64 dwords.
#pragma unroll
      for (int q = 0; q < 8; ++q)
#pragma unroll
        for (int d = 0; d < 4; ++d) {
          rH[q * 4 + d] = __hip_atomic_load(hbH + (w * 8 + q) * 256 + d,
                                            __ATOMIC_RELAXED,
                                            __HIP_MEMORY_SCOPE_AGENT);
          rL[q * 4 + d] = __hip_atomic_load(hbL + (w * 8 + q) * 256 + d,
                                            __ATOMIC_RELAXED,
                                            __HIP_MEMORY_SCOPE_AGENT);
        }
#pragma unroll
      for (int q = 0; q < 8; ++q) {
        union { unsigned int u[4]; bf16x8 v; } aH, aL;
#pragma unroll
        for (int d = 0; d < 4; ++d) {
          aH.u[d] = rH[q * 4 + d];
          aL.u[d] = rL[q * 4 + d];
        }
        acc0 = __builtin_amdgcn_mfma_f32_32x32x16_bf16(aH.v, vH[0][q], acc0, 0, 0, 0);
        acc0 = __builtin_amdgcn_mfma_f32_32x32x16_bf16(aH.v, vL[0][q], acc0, 0, 0, 0);
        acc0 = __builtin_amdgcn_mfma_f32_32x32x16_bf16(aL.v, vH[0][q], acc0, 0, 0, 0);
        acc1 = __builtin_amdgcn_mfma_f32_32x32x16_bf16(aH.v, vH[1][q], acc1, 0, 0, 0);
        acc1 = __builtin_amdgcn_mfma_f32_32x32x16_bf16(aH.v, vL[1][q], acc1, 0, 0, 0);
        acc1 = __builtin_amdgcn_mfma_f32_32x32x16_bf16(aL.v, vH[1][q], acc1, 0, 0, 0);
      }
    }

    // ---- write partial C tiles (measured C/D layout), XOR-swizzled ----
    {
      const int colw = lane & 31;
      const int rbase = 4 * (lane >> 5);
#pragma unroll
      for (int r = 0; r < 16; ++r) {
        int row = (r & 3) + 8 * (r >> 2) + rbase;
        gbuf[gidx(0, w, row, colw)] = acc0[r];
        gbuf[gidx(1, w, row, colw)] = acc1[r];
      }
    }
    __syncthreads();

    // ---- cell update (1 hidden unit per thread) ----
    {
      float gf = Bf, gi = Bi, go = Bo, gg = Bg;
#pragma unroll
      for (int ww = 0; ww < 8; ++ww) {
        gf += gbuf[gidx(0, ww, b_, jl)];
        gi += gbuf[gidx(0, ww, b_, 16 + jl)];
        go += gbuf[gidx(1, ww, b_, jl)];
        gg += gbuf[gidx(1, ww, b_, 16 + jl)];
      }
      float fs = sigm(gf), is = sigm(gi), os = sigm(go), gt = tanh_(gg);
      c = fs * c + is * gt;
      hcell[b_][jl] = os * tanh_(c);
    }
    __syncthreads();

    // ---- outputs (f32, nontemporal, coalesced 64B) + h publish (sc1) ----
    {
      const int b2 = tid >> 4, jj = tid & 15;
      float hv = hcell[b2][jj];
      __builtin_nontemporal_store(
          hv, out + 32768 + ((size_t)(b2 * T_STEPS + t)) * HID + wg * 16 + jj);
      if (t == T_STEPS - 1)
        __builtin_nontemporal_store(hv, out + (size_t)b2 * HID + wg * 16 + jj);
    }
    if (tid < 256) {
      const int b2 = tid >> 3, jp = tid & 7;
      float h0 = hcell[b2][2 * jp], h1 = hcell[b2][2 * jp + 1];
      unsigned short h0h = f2bf(h0), h1h = f2bf(h1);
      unsigned short h0l = f2bf(h0 - b2f(h0h)), h1l = f2bf(h1 - b2f(h1h));
      unsigned int hvH = (unsigned int)h0h | ((unsigned int)h1h << 16);
      unsigned int hvL = (unsigned int)h0l | ((unsigned int)h1l << 16);
      int hw = wg * 256 + (b2 + 32 * (jp >> 2)) * 4 + (jp & 3);
      __hip_atomic_store(&hfH[(size_t)(t & 3) * 16384 + hw], hvH, __ATOMIC_RELAXED,
                         __HIP_MEMORY_SCOPE_AGENT);
      __hip_atomic_store(&hfL[(size_t)(t & 3) * 16384 + hw], hvL, __ATOMIC_RELAXED,
                         __HIP_MEMORY_SCOPE_AGENT);
    }
    __syncthreads();  // vmcnt(0): sc1 publishes completed at coherence point
    if (tid == 0) {
      __hip_atomic_store(&flags[wg * 16], (unsigned int)(t + 1), __ATOMIC_RELAXED,
                         __HIP_MEMORY_SCOPE_AGENT);
    }
  }
}

// ================= r9 fallback (proven) =================
__global__ __launch_bounds__(256) void r9_step_gemm(
    const float* __restrict__ x, const float* __restrict__ hbuf,
    const float* __restrict__ Vf, const float* __restrict__ Vi,
    const float* __restrict__ Vo, const float* __restrict__ Vg,
    const float* __restrict__ Uf, const float* __restrict__ Ui,
    const float* __restrict__ Uo, const float* __restrict__ Ug,
    float* __restrict__ P, int t) {
  const int kb = blockIdx.x;
  const int cb = blockIdx.y;
  const int tidx = threadIdx.x;
  const int gate = cb >> 2;
  const int j = (cb & 3) * 256 + tidx;
  const int col = cb * 256 + tidx;
  const float* V_ = (gate == 0) ? Vf : (gate == 1) ? Vi : (gate == 2) ? Vo : Vg;
  const float* U_ = (gate == 0) ? Uf : (gate == 1) ? Ui : (gate == 2) ? Uo : Ug;
  __shared__ float hs[BS][32];
  __shared__ float xs2[BS][32];
  {
    int idx = tidx * 4;
#pragma unroll
    for (int i = 0; i < 4; ++i, ++idx) {
      int b = idx >> 5, u = idx & 31;
      hs[b][u] = hbuf[b * HID + kb * 32 + u];
      if (kb < 16) xs2[b][u] = x[((size_t)b * T_STEPS + t) * 512 + kb * 32 + u];
    }
  }
  __syncthreads();
  float acc[BS];
#pragma unroll
  for (int b = 0; b < BS; ++b) acc[b] = 0.f;
  const float* vp = V_ + (size_t)(kb * 32) * HID + j;
#pragma unroll 4
  for (int k = 0; k < 32; ++k) {
    float vv = vp[(size_t)k * HID];
#pragma unroll
    for (int b = 0; b < BS; ++b) acc[b] += hs[b][k] * vv;
  }
  if (kb < 16) {
    const float* up = U_ + (size_t)(kb * 32) * HID + j;
#pragma unroll 4
    for (int k = 0; k < 32; ++k) {
      float uv = up[(size_t)k * HID];
#pragma unroll
      for (int b = 0; b < BS; ++b) acc[b] += xs2[b][k] * uv;
    }
  }
  float* pp = P + (size_t)kb * BS * 4096 + col;
#pragma unroll
  for (int b = 0; b < BS; ++b) pp[(size_t)b * 4096] = acc[b];
}

__global__ __launch_bounds__(256) void r9_step_cell(
    const float* __restrict__ P,
    const float* __restrict__ bfv, const float* __restrict__ biv,
    const float* __restrict__ bov, const float* __restrict__ bgv,
    float* __restrict__ hbuf, float* __restrict__ cbuf,
    float* __restrict__ out, int t) {
  const int idx = blockIdx.x * 256 + threadIdx.x;
  const int b = idx >> 10, j = idx & 1023;
  float gf = bfv[j], gi = biv[j], go = bov[j], gg = bgv[j];
  const float* pb = P + (size_t)b * 4096;
#pragma unroll 8
  for (int kb = 0; kb < 32; ++kb) {
    const float* pk = pb + (size_t)kb * BS * 4096;
    gf += pk[j];
    gi += pk[1024 + j];
    go += pk[2048 + j];
    gg += pk[3072 + j];
  }
  float fs = sigm(gf), is = sigm(gi), os = sigm(go), gt = tanh_(gg);
  float c = fs * cbuf[idx] + is * gt;
  cbuf[idx] = c;
  float h = os * tanh_(c);
  hbuf[idx] = h;
  out[32768 + ((size_t)b * T_STEPS + t) * HID + j] = h;
  if (t == T_STEPS - 1) out[(size_t)b * HID + j] = h;
}

extern "C" void kernel_launch(void* const* d_in, const int* in_sizes, int n_in,
                              void* d_out, int out_size, void* d_ws, size_t ws_size,
                              hipStream_t stream) {
  const float *x, *Uf, *Vf, *bf, *Ui, *Vi, *bi, *Uo, *Vo, *bo, *Ug, *Vg, *bg;
  float* out = (float*)d_out;

  bool okA = (n_in == 13) && in_sizes[0] == 8388608 && in_sizes[1] == 524288 &&
             in_sizes[2] == 1048576 && in_sizes[3] == 1024 &&
             in_sizes[4] == 524288 && in_sizes[7] == 524288 &&
             in_sizes[10] == 524288 && in_sizes[12] == 1024;
  if (okA) {
    x = (const float*)d_in[0];
    Uf = (const float*)d_in[1];  Vf = (const float*)d_in[2];  bf = (const float*)d_in[3];
    Ui = (const float*)d_in[4];  Vi = (const float*)d_in[5];  bi = (const float*)d_in[6];
    Uo = (const float*)d_in[7];  Vo = (const float*)d_in[8];  bo = (const float*)d_in[9];
    Ug = (const float*)d_in[10]; Vg = (const float*)d_in[11]; bg = (const float*)d_in[12];
  } else {
    Uf = (const float*)d_in[0];  Ug = (const float*)d_in[1];
    Ui = (const float*)d_in[2];  Uo = (const float*)d_in[3];
    Vf = (const float*)d_in[4];  Vg = (const float*)d_in[5];
    Vi = (const float*)d_in[6];  Vo = (const float*)d_in[7];
    bf = (const float*)d_in[8];  bg = (const float*)d_in[9];
    bi = (const float*)d_in[10]; bo = (const float*)d_in[11];
    x = (const float*)d_in[12];
  }

  char* ws = (char*)d_ws;
  if (ws_size >= (size_t)WS_FAST) {
    unsigned int* flags = (unsigned int*)(ws + 0);
    unsigned int* hfH = (unsigned int*)(ws + 65536);
    unsigned int* hfL = (unsigned int*)(ws + 327680);
    unsigned short* vfragH = (unsigned short*)(ws + 1048576);
    unsigned short* vfragL = (unsigned short*)(ws + 9437184);
    unsigned short* ufragH = (unsigned short*)(ws + 17825792);
    unsigned short* ufragL = (unsigned short*)(ws + 22020096);
    unsigned short* xfragH = (unsigned short*)(ws + 26214400);
    unsigned short* xfragL = (unsigned short*)(ws + 42991616);

    (void)hipMemsetAsync(flags, 0, 4096, stream);
    cvt_uv_kernel<<<64 * 2 * 96, 64, 0, stream>>>(
        Uf, Vf, Ui, Vi, Uo, Vo, Ug, Vg, (unsigned int*)vfragH, (unsigned int*)vfragL,
        (unsigned int*)ufragH, (unsigned int*)ufragL);
    cvt_x_kernel<<<512, 256, 0, stream>>>(x, (unsigned int*)xfragH,
                                          (unsigned int*)xfragL);
    lstm_main_kernel<<<NWG, 512, 0, stream>>>(ufragH, ufragL, vfragH, vfragL, xfragH,
                                              xfragL, hfH, hfL, flags, bf, bi, bo,
                                              bg, out);
  } else {
    float* P = (float*)ws;
    float* hbuf = (float*)(ws + 16777216);
    float* cbuf = (float*)(ws + 16908288);
    (void)hipMemsetAsync(hbuf, 0, 131072, stream);
    (void)hipMemsetAsync(cbuf, 0, 131072, stream);
    for (int t = 0; t < T_STEPS; ++t) {
      r9_step_gemm<<<dim3(32, 16), 256, 0, stream>>>(x, hbuf, Vf, Vi, Vo, Vg, Uf, Ui,
                                                     Uo, Ug, P, t);
      r9_step_cell<<<128, 256, 0, stream>>>(P, bf, bi, bo, bg, hbuf, cbuf, out, t);
    }
  }
}

// Round 12
// 5852.982 us; speedup vs baseline: 2.2592x; 1.0296x over previous
//
#include <hip/hip_runtime.h>

// CustomLSTM — Round 12: r11 + two critical-path fixes.
//   (1) flags CONTIGUOUS (4B stride): wave-0 poll = 4 coalesced lines instead
//       of 64 scattered lines -> 16x less L3 poll traffic (64 WGs polling).
//   (2) hidden_seq/h_last stores moved AFTER the flag release: their HBM ack
//       no longer sits on the 512-step serial chain (values captured in VGPR
//       before issue, so no LDS-overwrite hazard).
// Everything else identical to r11 (green, 6035 us).
//
// Fast-path ws layout (57 MB):
//   0         flags   4096        (contiguous dwords, one per WG)
//   65536     hfH     262144      (4-slot ring, bf16 A-frag hi)
//   327680    hfL     262144      (lo plane)
//   1048576   vfragH  8388608     | 9437184  vfragL 8388608
//   17825792  ufragH  4194304     | 22020096 ufragL 4194304
//   26214400  xfragH 16777216     | 42991616 xfragL 16777216  (end 59768832)

typedef __bf16 bf16x8 __attribute__((ext_vector_type(8)));
typedef float f32x16 __attribute__((ext_vector_type(16)));

#define NWG 64
#define T_STEPS 512
#define HID 1024
#define BS 32
#define WS_FAST 59768832

__device__ __forceinline__ unsigned short f2bf(float f) {
  unsigned int u = __float_as_uint(f);
  u = (u + 0x7FFFu + ((u >> 16) & 1u)) >> 16;
  return (unsigned short)u;
}
__device__ __forceinline__ float b2f(unsigned short s) {
  return __uint_as_float(((unsigned int)s) << 16);
}
__device__ __forceinline__ float sigm(float v) {
  v = fminf(fmaxf(v, -30.f), 30.f);
  return 1.f / (1.f + __expf(-v));
}
__device__ __forceinline__ float tanh_(float v) {
  v = fminf(fmaxf(v, -15.f), 15.f);
  float e = __expf(-2.f * v);
  return (1.f - e) / (1.f + e);
}

// ---- x -> bf16 A-frags hi+lo: [t][kt 0..31][lane][4 dwords] ----
// A-frag map (32x32x16): row b = lane&31, k = 8*(lane>>5) + 2r + {0,1}
__global__ void cvt_x_kernel(const float* __restrict__ x,
                             unsigned int* __restrict__ xfH,
                             unsigned int* __restrict__ xfL) {
  const int t = blockIdx.x;
  const int tid = threadIdx.x;
  __shared__ float xs[32 * 512];
  {
    const int b = tid >> 3;
    const int k0 = (tid & 7) * 64;
    const float* src = x + ((size_t)(b * 512 + t)) * 512 + k0;
    for (int i = 0; i < 64; i += 4) {
      float4 v = *reinterpret_cast<const float4*>(src + i);
      xs[b * 512 + k0 + i + 0] = v.x;
      xs[b * 512 + k0 + i + 1] = v.y;
      xs[b * 512 + k0 + i + 2] = v.z;
      xs[b * 512 + k0 + i + 3] = v.w;
    }
  }
  __syncthreads();
  unsigned int* dH = xfH + (size_t)t * 8192;
  unsigned int* dL = xfL + (size_t)t * 8192;
  for (int i = 0; i < 32; ++i) {
    int idx = i * 256 + tid;
    int kt = idx >> 8;
    int pos = idx & 255;
    int lane = pos >> 2;
    int r = pos & 3;
    int kk = 8 * (lane >> 5) + 2 * r;
    int b2 = lane & 31;
    float f0 = xs[b2 * 512 + kt * 16 + kk];
    float f1 = xs[b2 * 512 + kt * 16 + kk + 1];
    unsigned short h0 = f2bf(f0), h1 = f2bf(f1);
    unsigned short l0 = f2bf(f0 - b2f(h0)), l1 = f2bf(f1 - b2f(h1));
    dH[idx] = (unsigned int)h0 | ((unsigned int)h1 << 16);
    dL[idx] = (unsigned int)l0 | ((unsigned int)l1 << 16);
  }
}

// ---- U,V -> B-frags hi+lo. V: kt 0..63. U: kt 64..95 ----
__global__ void cvt_uv_kernel(const float* Uf, const float* Vf,
                              const float* Ui, const float* Vi,
                              const float* Uo, const float* Vo,
                              const float* Ug, const float* Vg,
                              unsigned int* __restrict__ vfH,
                              unsigned int* __restrict__ vfL,
                              unsigned int* __restrict__ ufH,
                              unsigned int* __restrict__ ufL) {
  int blk = blockIdx.x;  // 64*2*96
  int kt = blk % 96;
  int nt = (blk / 96) & 1;
  int wg = blk / 192;
  int lane = threadIdx.x;
  int col32 = lane & 31;
  int c64 = nt * 32 + col32;
  int gate = c64 >> 4;
  int jg = wg * 16 + (c64 & 15);
  const float* V_ = (gate == 0) ? Vf : (gate == 1) ? Vi : (gate == 2) ? Vo : Vg;
  const float* U_ = (gate == 0) ? Uf : (gate == 1) ? Ui : (gate == 2) ? Uo : Ug;
  for (int r = 0; r < 4; ++r) {
    int kk = 8 * (lane >> 5) + 2 * r;
    if (kt < 64) {
      int K = kt * 16 + kk;
      float f0 = V_[(size_t)K * HID + jg];
      float f1 = V_[(size_t)(K + 1) * HID + jg];
      unsigned short h0 = f2bf(f0), h1 = f2bf(f1);
      unsigned short l0 = f2bf(f0 - b2f(h0)), l1 = f2bf(f1 - b2f(h1));
      size_t idx = ((size_t)(wg * 2 + nt) * 64 + kt) * 256 + lane * 4 + r;
      vfH[idx] = (unsigned int)h0 | ((unsigned int)h1 << 16);
      vfL[idx] = (unsigned int)l0 | ((unsigned int)l1 << 16);
    } else {
      int K = (kt - 64) * 16 + kk;
      float f0 = U_[(size_t)K * HID + jg];
      float f1 = U_[(size_t)(K + 1) * HID + jg];
      unsigned short h0 = f2bf(f0), h1 = f2bf(f1);
      unsigned short l0 = f2bf(f0 - b2f(h0)), l1 = f2bf(f1 - b2f(h1));
      size_t idx = ((size_t)(wg * 2 + nt) * 32 + (kt - 64)) * 256 + lane * 4 + r;
      ufH[idx] = (unsigned int)h0 | ((unsigned int)h1 << 16);
      ufL[idx] = (unsigned int)l0 | ((unsigned int)l1 << 16);
    }
  }
}

__device__ __forceinline__ int gidx(int nt, int w, int row, int col) {
  return ((nt * 8 + w) * 32 + row) * 32 + (col ^ row);
}

// ---- persistent recurrent kernel: 64 WGs x 512 threads (8 waves) ----
__global__ __launch_bounds__(512, 2) void lstm_main_kernel(
    const unsigned short* __restrict__ ufragH,
    const unsigned short* __restrict__ ufragL,
    const unsigned short* __restrict__ vfragH,
    const unsigned short* __restrict__ vfragL,
    const unsigned short* __restrict__ xfragH,
    const unsigned short* __restrict__ xfragL,
    unsigned int* hfH, unsigned int* hfL, unsigned int* flags,
    const float* __restrict__ bfv, const float* __restrict__ biv,
    const float* __restrict__ bov, const float* __restrict__ bgv,
    float* __restrict__ out) {
  __shared__ unsigned short ldsU[2 * 32 * 512];  // 64 KB: U hi frags
  __shared__ float gbuf[2 * 8 * 32 * 32];        // 64 KB, XOR-swizzled
  __shared__ float hcell[32][17];

  const int wg = blockIdx.x;
  const int tid = threadIdx.x;
  const int lane = tid & 63;
  const int w = tid >> 6;

  {
    const bf16x8* src = reinterpret_cast<const bf16x8*>(ufragH + (size_t)wg * 32768);
    bf16x8* dst = reinterpret_cast<bf16x8*>(ldsU);
    for (int i = 0; i < 8; ++i) dst[i * 512 + tid] = src[i * 512 + tid];
  }
  __syncthreads();
  __builtin_amdgcn_fence(__ATOMIC_ACQUIRE, "agent");  // once: replay-stale kill

  bf16x8 uL[2][4], vH[2][8], vL[2][8];
#pragma unroll
  for (int nt = 0; nt < 2; ++nt) {
    const bf16x8* bl = reinterpret_cast<const bf16x8*>(ufragL + (size_t)wg * 32768) +
                       (size_t)nt * 32 * 64;
#pragma unroll
    for (int p = 0; p < 4; ++p) uL[nt][p] = bl[(w * 4 + p) * 64 + lane];
    const bf16x8* vh =
        reinterpret_cast<const bf16x8*>(vfragH + (size_t)((wg * 2 + nt) * 64) * 512);
    const bf16x8* vl =
        reinterpret_cast<const bf16x8*>(vfragL + (size_t)((wg * 2 + nt) * 64) * 512);
#pragma unroll
    for (int q = 0; q < 8; ++q) {
      vH[nt][q] = vh[(w * 8 + q) * 64 + lane];
      vL[nt][q] = vl[(w * 8 + q) * 64 + lane];
    }
  }

  const int b_ = tid & 31;
  const int jl = tid >> 5;  // 0..15
  const int jg = wg * 16 + jl;
  const float Bf = bfv[jg], Bi = biv[jg], Bo = bov[jg], Bg = bgv[jg];
  float c = 0.f;

#pragma unroll 1
  for (int t = 0; t < T_STEPS; ++t) {
    f32x16 acc0 = {};
    f32x16 acc1 = {};

    // ---- x@U hi+lo (no h dependency: issued before the flag wait) ----
    {
      const bf16x8* axh = reinterpret_cast<const bf16x8*>(xfragH + (size_t)t * 16384);
      const bf16x8* axl = reinterpret_cast<const bf16x8*>(xfragL + (size_t)t * 16384);
      const bf16x8* lu = reinterpret_cast<const bf16x8*>(ldsU);
#pragma unroll
      for (int p = 0; p < 4; ++p) {
        int ktx = w * 4 + p;
        bf16x8 ah = axh[ktx * 64 + lane];
        bf16x8 al = axl[ktx * 64 + lane];
        bf16x8 u0 = lu[ktx * 64 + lane];
        bf16x8 u1 = lu[(32 + ktx) * 64 + lane];
        acc0 = __builtin_amdgcn_mfma_f32_32x32x16_bf16(ah, u0, acc0, 0, 0, 0);
        acc0 = __builtin_amdgcn_mfma_f32_32x32x16_bf16(ah, uL[0][p], acc0, 0, 0, 0);
        acc0 = __builtin_amdgcn_mfma_f32_32x32x16_bf16(al, u0, acc0, 0, 0, 0);
        acc1 = __builtin_amdgcn_mfma_f32_32x32x16_bf16(ah, u1, acc1, 0, 0, 0);
        acc1 = __builtin_amdgcn_mfma_f32_32x32x16_bf16(ah, uL[1][p], acc1, 0, 0, 0);
        acc1 = __builtin_amdgcn_mfma_f32_32x32x16_bf16(al, u1, acc1, 0, 0, 0);
      }
    }

    // ---- wait all h_{t-1} (coalesced contiguous-flag poll), then h@V ----
    if (t > 0) {
      if (tid < NWG) {
        while (__hip_atomic_load(&flags[tid], __ATOMIC_RELAXED,
                                 __HIP_MEMORY_SCOPE_AGENT) < (unsigned int)t) {
        }
      }
      __syncthreads();
      const unsigned int* hbH = hfH + (size_t)((t - 1) & 3) * 16384 + lane * 4;
      const unsigned int* hbL = hfL + (size_t)((t - 1) & 3) * 16384 + lane * 4;
      unsigned int rH[32], rL[32];
#pragma unroll
      for (int q = 0; q < 8; ++q)
#pragma unroll
        for (int d = 0; d < 4; ++d) {
          rH[q * 4 + d] = __hip_atomic_load(hbH + (w * 8 + q) * 256 + d,
                                            __ATOMIC_RELAXED,
                                            __HIP_MEMORY_SCOPE_AGENT);
          rL[q * 4 + d] = __hip_atomic_load(hbL + (w * 8 + q) * 256 + d,
                                            __ATOMIC_RELAXED,
                                            __HIP_MEMORY_SCOPE_AGENT);
        }
#pragma unroll
      for (int q = 0; q < 8; ++q) {
        union { unsigned int u[4]; bf16x8 v; } aH, aL;
#pragma unroll
        for (int d = 0; d < 4; ++d) {
          aH.u[d] = rH[q * 4 + d];
          aL.u[d] = rL[q * 4 + d];
        }
        acc0 = __builtin_amdgcn_mfma_f32_32x32x16_bf16(aH.v, vH[0][q], acc0, 0, 0, 0);
        acc0 = __builtin_amdgcn_mfma_f32_32x32x16_bf16(aH.v, vL[0][q], acc0, 0, 0, 0);
        acc0 = __builtin_amdgcn_mfma_f32_32x32x16_bf16(aL.v, vH[0][q], acc0, 0, 0, 0);
        acc1 = __builtin_amdgcn_mfma_f32_32x32x16_bf16(aH.v, vH[1][q], acc1, 0, 0, 0);
        acc1 = __builtin_amdgcn_mfma_f32_32x32x16_bf16(aH.v, vL[1][q], acc1, 0, 0, 0);
        acc1 = __builtin_amdgcn_mfma_f32_32x32x16_bf16(aL.v, vH[1][q], acc1, 0, 0, 0);
      }
    }

    // ---- write partial C tiles (measured C/D layout), XOR-swizzled ----
    {
      const int colw = lane & 31;
      const int rbase = 4 * (lane >> 5);
#pragma unroll
      for (int r = 0; r < 16; ++r) {
        int row = (r & 3) + 8 * (r >> 2) + rbase;
        gbuf[gidx(0, w, row, colw)] = acc0[r];
        gbuf[gidx(1, w, row, colw)] = acc1[r];
      }
    }
    __syncthreads();

    // ---- cell update (1 hidden unit per thread) ----
    {
      float gf = Bf, gi = Bi, go = Bo, gg = Bg;
#pragma unroll
      for (int ww = 0; ww < 8; ++ww) {
        gf += gbuf[gidx(0, ww, b_, jl)];
        gi += gbuf[gidx(0, ww, b_, 16 + jl)];
        go += gbuf[gidx(1, ww, b_, jl)];
        gg += gbuf[gidx(1, ww, b_, 16 + jl)];
      }
      float fs = sigm(gf), is = sigm(gi), os = sigm(go), gt = tanh_(gg);
      c = fs * c + is * gt;
      hcell[b_][jl] = os * tanh_(c);
    }
    __syncthreads();

    // ---- publish h (sc1) -> drain -> flag release -> THEN out stores ----
    if (tid < 256) {
      const int b2 = tid >> 3, jp = tid & 7;
      float h0 = hcell[b2][2 * jp], h1 = hcell[b2][2 * jp + 1];
      unsigned short h0h = f2bf(h0), h1h = f2bf(h1);
      unsigned short h0l = f2bf(h0 - b2f(h0h)), h1l = f2bf(h1 - b2f(h1h));
      unsigned int hvH = (unsigned int)h0h | ((unsigned int)h1h << 16);
      unsigned int hvL = (unsigned int)h0l | ((unsigned int)h1l << 16);
      int hw = wg * 256 + (b2 + 32 * (jp >> 2)) * 4 + (jp & 3);
      __hip_atomic_store(&hfH[(size_t)(t & 3) * 16384 + hw], hvH, __ATOMIC_RELAXED,
                         __HIP_MEMORY_SCOPE_AGENT);
      __hip_atomic_store(&hfL[(size_t)(t & 3) * 16384 + hw], hvL, __ATOMIC_RELAXED,
                         __HIP_MEMORY_SCOPE_AGENT);
    }
    __syncthreads();  // vmcnt(0): publishes completed at coherence point
    if (tid == 0) {
      __hip_atomic_store(&flags[wg], (unsigned int)(t + 1), __ATOMIC_RELAXED,
                         __HIP_MEMORY_SCOPE_AGENT);
    }
    // out stores AFTER the release: off the inter-WG critical path (values
    // captured from LDS into VGPRs before issue; hcell not yet overwritten).
    {
      const int b2 = tid >> 4, jj = tid & 15;
      float hv = hcell[b2][jj];
      __builtin_nontemporal_store(
          hv, out + 32768 + ((size_t)(b2 * T_STEPS + t)) * HID + wg * 16 + jj);
      if (t == T_STEPS - 1)
        __builtin_nontemporal_store(hv, out + (size_t)b2 * HID + wg * 16 + jj);
    }
  }
}

// ================= r9 fallback (proven) =================
__global__ __launch_bounds__(256) void r9_step_gemm(
    const float* __restrict__ x, const float* __restrict__ hbuf,
    const float* __restrict__ Vf, const float* __restrict__ Vi,
    const float* __restrict__ Vo, const float* __restrict__ Vg,
    const float* __restrict__ Uf, const float* __restrict__ Ui,
    const float* __restrict__ Uo, const float* __restrict__ Ug,
    float* __restrict__ P, int t) {
  const int kb = blockIdx.x;
  const int cb = blockIdx.y;
  const int tidx = threadIdx.x;
  const int gate = cb >> 2;
  const int j = (cb & 3) * 256 + tidx;
  const int col = cb * 256 + tidx;
  const float* V_ = (gate == 0) ? Vf : (gate == 1) ? Vi : (gate == 2) ? Vo : Vg;
  const float* U_ = (gate == 0) ? Uf : (gate == 1) ? Ui : (gate == 2) ? Uo : Ug;
  __shared__ float hs[BS][32];
  __shared__ float xs2[BS][32];
  {
    int idx = tidx * 4;
#pragma unroll
    for (int i = 0; i < 4; ++i, ++idx) {
      int b = idx >> 5, u = idx & 31;
      hs[b][u] = hbuf[b * HID + kb * 32 + u];
      if (kb < 16) xs2[b][u] = x[((size_t)b * T_STEPS + t) * 512 + kb * 32 + u];
    }
  }
  __syncthreads();
  float acc[BS];
#pragma unroll
  for (int b = 0; b < BS; ++b) acc[b] = 0.f;
  const float* vp = V_ + (size_t)(kb * 32) * HID + j;
#pragma unroll 4
  for (int k = 0; k < 32; ++k) {
    float vv = vp[(size_t)k * HID];
#pragma unroll
    for (int b = 0; b < BS; ++b) acc[b] += hs[b][k] * vv;
  }
  if (kb < 16) {
    const float* up = U_ + (size_t)(kb * 32) * HID + j;
#pragma unroll 4
    for (int k = 0; k < 32; ++k) {
      float uv = up[(size_t)k * HID];
#pragma unroll
      for (int b = 0; b < BS; ++b) acc[b] += xs2[b][k] * uv;
    }
  }
  float* pp = P + (size_t)kb * BS * 4096 + col;
#pragma unroll
  for (int b = 0; b < BS; ++b) pp[(size_t)b * 4096] = acc[b];
}

__global__ __launch_bounds__(256) void r9_step_cell(
    const float* __restrict__ P,
    const float* __restrict__ bfv, const float* __restrict__ biv,
    const float* __restrict__ bov, const float* __restrict__ bgv,
    float* __restrict__ hbuf, float* __restrict__ cbuf,
    float* __restrict__ out, int t) {
  const int idx = blockIdx.x * 256 + threadIdx.x;
  const int b = idx >> 10, j = idx & 1023;
  float gf = bfv[j], gi = biv[j], go = bov[j], gg = bgv[j];
  const float* pb = P + (size_t)b * 4096;
#pragma unroll 8
  for (int kb = 0; kb < 32; ++kb) {
    const float* pk = pb + (size_t)kb * BS * 4096;
    gf += pk[j];
    gi += pk[1024 + j];
    go += pk[2048 + j];
    gg += pk[3072 + j];
  }
  float fs = sigm(gf), is = sigm(gi), os = sigm(go), gt = tanh_(gg);
  float c = fs * cbuf[idx] + is * gt;
  cbuf[idx] = c;
  float h = os * tanh_(c);
  hbuf[idx] = h;
  out[32768 + ((size_t)b * T_STEPS + t) * HID + j] = h;
  if (t == T_STEPS - 1) out[(size_t)b * HID + j] = h;
}

extern "C" void kernel_launch(void* const* d_in, const int* in_sizes, int n_in,
                              void* d_out, int out_size, void* d_ws, size_t ws_size,
                              hipStream_t stream) {
  const float *x, *Uf, *Vf, *bf, *Ui, *Vi, *bi, *Uo, *Vo, *bo, *Ug, *Vg, *bg;
  float* out = (float*)d_out;

  bool okA = (n_in == 13) && in_sizes[0] == 8388608 && in_sizes[1] == 524288 &&
             in_sizes[2] == 1048576 && in_sizes[3] == 1024 &&
             in_sizes[4] == 524288 && in_sizes[7] == 524288 &&
             in_sizes[10] == 524288 && in_sizes[12] == 1024;
  if (okA) {
    x = (const float*)d_in[0];
    Uf = (const float*)d_in[1];  Vf = (const float*)d_in[2];  bf = (const float*)d_in[3];
    Ui = (const float*)d_in[4];  Vi = (const float*)d_in[5];  bi = (const float*)d_in[6];
    Uo = (const float*)d_in[7];  Vo = (const float*)d_in[8];  bo = (const float*)d_in[9];
    Ug = (const float*)d_in[10]; Vg = (const float*)d_in[11]; bg = (const float*)d_in[12];
  } else {
    Uf = (const float*)d_in[0];  Ug = (const float*)d_in[1];
    Ui = (const float*)d_in[2];  Uo = (const float*)d_in[3];
    Vf = (const float*)d_in[4];  Vg = (const float*)d_in[5];
    Vi = (const float*)d_in[6];  Vo = (const float*)d_in[7];
    bf = (const float*)d_in[8];  bg = (const float*)d_in[9];
    bi = (const float*)d_in[10]; bo = (const float*)d_in[11];
    x = (const float*)d_in[12];
  }

  char* ws = (char*)d_ws;
  if (ws_size >= (size_t)WS_FAST) {
    unsigned int* flags = (unsigned int*)(ws + 0);
    unsigned int* hfH = (unsigned int*)(ws + 65536);
    unsigned int* hfL = (unsigned int*)(ws + 327680);
    unsigned short* vfragH = (unsigned short*)(ws + 1048576);
    unsigned short* vfragL = (unsigned short*)(ws + 9437184);
    unsigned short* ufragH = (unsigned short*)(ws + 17825792);
    unsigned short* ufragL = (unsigned short*)(ws + 22020096);
    unsigned short* xfragH = (unsigned short*)(ws + 26214400);
    unsigned short* xfragL = (unsigned short*)(ws + 42991616);

    (void)hipMemsetAsync(flags, 0, 4096, stream);
    cvt_uv_kernel<<<64 * 2 * 96, 64, 0, stream>>>(
        Uf, Vf, Ui, Vi, Uo, Vo, Ug, Vg, (unsigned int*)vfragH, (unsigned int*)vfragL,
        (unsigned int*)ufragH, (unsigned int*)ufragL);
    cvt_x_kernel<<<512, 256, 0, stream>>>(x, (unsigned int*)xfragH,
                                          (unsigned int*)xfragL);
    lstm_main_kernel<<<NWG, 512, 0, stream>>>(ufragH, ufragL, vfragH, vfragL, xfragH,
                                              xfragL, hfH, hfL, flags, bf, bi, bo,
                                              bg, out);
  } else {
    float* P = (float*)ws;
    float* hbuf = (float*)(ws + 16777216);
    float* cbuf = (float*)(ws + 16908288);
    (void)hipMemsetAsync(hbuf, 0, 131072, stream);
    (void)hipMemsetAsync(cbuf, 0, 131072, stream);
    for (int t = 0; t < T_STEPS; ++t) {
      r9_step_gemm<<<dim3(32, 16), 256, 0, stream>>>(x, hbuf, Vf, Vi, Vo, Vg, Uf, Ui,
                                                     Uo, Ug, P, t);
      r9_step_cell<<<128, 256, 0, stream>>>(P, bf, bi, bo, bg, hbuf, cbuf, out, t);
    }
  }
}

// Round 13
// 3888.121 us; speedup vs baseline: 3.4009x; 1.5053x over previous
//
#include <hip/hip_runtime.h>

// CustomLSTM — Round 13: address-unique per-step h buffers (no ring) read with
// NORMAL cached loads (L2-shared within XCD, dwordx4-coalesced) instead of 64
// scalar sc1 dword atomic-loads per lane. Producers still sc1-publish (L3
// write-through); start-of-kernel acquire fence kills cross-replay stale L2
// lines; within a replay every h line is written-before-first-read.
// Cell update: 256 thr x 2 units -> publish straight from registers (one
// fewer barrier on the critical path). Launcher tiers: full-seq (121MB ws) ->
// r12 ring (57MB) -> r9 slow path.
//
// Full ws layout:
//   0         flags   4096
//   1048576   vfragH  8388608   | 9437184  vfragL 8388608
//   17825792  ufragH  4194304   | 22020096 ufragL 4194304
//   26214400  xfragH 16777216   | 42991616 xfragL 16777216
//   59768832  hSeqH  33554432   | 93323264 hSeqL 33554432   (end 126877696)

typedef __bf16 bf16x8 __attribute__((ext_vector_type(8)));
typedef float f32x16 __attribute__((ext_vector_type(16)));

#define NWG 64
#define T_STEPS 512
#define HID 1024
#define BS 32
#define WS_RING 59768832
#define WS_FULL 126877696

__device__ __forceinline__ unsigned short f2bf(float f) {
  unsigned int u = __float_as_uint(f);
  u = (u + 0x7FFFu + ((u >> 16) & 1u)) >> 16;
  return (unsigned short)u;
}
__device__ __forceinline__ float b2f(unsigned short s) {
  return __uint_as_float(((unsigned int)s) << 16);
}
__device__ __forceinline__ float sigm(float v) {
  v = fminf(fmaxf(v, -30.f), 30.f);
  return 1.f / (1.f + __expf(-v));
}
__device__ __forceinline__ float tanh_(float v) {
  v = fminf(fmaxf(v, -15.f), 15.f);
  float e = __expf(-2.f * v);
  return (1.f - e) / (1.f + e);
}

// ---- x -> bf16 A-frags hi+lo: [t][kt 0..31][lane][4 dwords] ----
__global__ void cvt_x_kernel(const float* __restrict__ x,
                             unsigned int* __restrict__ xfH,
                             unsigned int* __restrict__ xfL) {
  const int t = blockIdx.x;
  const int tid = threadIdx.x;
  __shared__ float xs[32 * 512];
  {
    const int b = tid >> 3;
    const int k0 = (tid & 7) * 64;
    const float* src = x + ((size_t)(b * 512 + t)) * 512 + k0;
    for (int i = 0; i < 64; i += 4) {
      float4 v = *reinterpret_cast<const float4*>(src + i);
      xs[b * 512 + k0 + i + 0] = v.x;
      xs[b * 512 + k0 + i + 1] = v.y;
      xs[b * 512 + k0 + i + 2] = v.z;
      xs[b * 512 + k0 + i + 3] = v.w;
    }
  }
  __syncthreads();
  unsigned int* dH = xfH + (size_t)t * 8192;
  unsigned int* dL = xfL + (size_t)t * 8192;
  for (int i = 0; i < 32; ++i) {
    int idx = i * 256 + tid;
    int kt = idx >> 8;
    int pos = idx & 255;
    int lane = pos >> 2;
    int r = pos & 3;
    int kk = 8 * (lane >> 5) + 2 * r;
    int b2 = lane & 31;
    float f0 = xs[b2 * 512 + kt * 16 + kk];
    float f1 = xs[b2 * 512 + kt * 16 + kk + 1];
    unsigned short h0 = f2bf(f0), h1 = f2bf(f1);
    unsigned short l0 = f2bf(f0 - b2f(h0)), l1 = f2bf(f1 - b2f(h1));
    dH[idx] = (unsigned int)h0 | ((unsigned int)h1 << 16);
    dL[idx] = (unsigned int)l0 | ((unsigned int)l1 << 16);
  }
}

// ---- U,V -> B-frags hi+lo. V: kt 0..63. U: kt 64..95 ----
__global__ void cvt_uv_kernel(const float* Uf, const float* Vf,
                              const float* Ui, const float* Vi,
                              const float* Uo, const float* Vo,
                              const float* Ug, const float* Vg,
                              unsigned int* __restrict__ vfH,
                              unsigned int* __restrict__ vfL,
                              unsigned int* __restrict__ ufH,
                              unsigned int* __restrict__ ufL) {
  int blk = blockIdx.x;  // 64*2*96
  int kt = blk % 96;
  int nt = (blk / 96) & 1;
  int wg = blk / 192;
  int lane = threadIdx.x;
  int col32 = lane & 31;
  int c64 = nt * 32 + col32;
  int gate = c64 >> 4;
  int jg = wg * 16 + (c64 & 15);
  const float* V_ = (gate == 0) ? Vf : (gate == 1) ? Vi : (gate == 2) ? Vo : Vg;
  const float* U_ = (gate == 0) ? Uf : (gate == 1) ? Ui : (gate == 2) ? Uo : Ug;
  for (int r = 0; r < 4; ++r) {
    int kk = 8 * (lane >> 5) + 2 * r;
    if (kt < 64) {
      int K = kt * 16 + kk;
      float f0 = V_[(size_t)K * HID + jg];
      float f1 = V_[(size_t)(K + 1) * HID + jg];
      unsigned short h0 = f2bf(f0), h1 = f2bf(f1);
      unsigned short l0 = f2bf(f0 - b2f(h0)), l1 = f2bf(f1 - b2f(h1));
      size_t idx = ((size_t)(wg * 2 + nt) * 64 + kt) * 256 + lane * 4 + r;
      vfH[idx] = (unsigned int)h0 | ((unsigned int)h1 << 16);
      vfL[idx] = (unsigned int)l0 | ((unsigned int)l1 << 16);
    } else {
      int K = (kt - 64) * 16 + kk;
      float f0 = U_[(size_t)K * HID + jg];
      float f1 = U_[(size_t)(K + 1) * HID + jg];
      unsigned short h0 = f2bf(f0), h1 = f2bf(f1);
      unsigned short l0 = f2bf(f0 - b2f(h0)), l1 = f2bf(f1 - b2f(h1));
      size_t idx = ((size_t)(wg * 2 + nt) * 32 + (kt - 64)) * 256 + lane * 4 + r;
      ufH[idx] = (unsigned int)h0 | ((unsigned int)h1 << 16);
      ufL[idx] = (unsigned int)l0 | ((unsigned int)l1 << 16);
    }
  }
}

__device__ __forceinline__ int gidx(int nt, int w, int row, int col) {
  return ((nt * 8 + w) * 32 + row) * 32 + (col ^ row);
}

// ---- persistent recurrent kernel: 64 WGs x 512 threads (8 waves) ----
// FULLSEQ=1: h in 512 address-unique per-step planes, NORMAL cached reads.
// FULLSEQ=0: r12 behavior (4-slot ring, sc1 dword reads).
template <int FULLSEQ>
__global__ __launch_bounds__(512, 2) void lstm_main(
    const unsigned short* __restrict__ ufragH,
    const unsigned short* __restrict__ ufragL,
    const unsigned short* __restrict__ vfragH,
    const unsigned short* __restrict__ vfragL,
    const unsigned short* __restrict__ xfragH,
    const unsigned short* __restrict__ xfragL,
    unsigned int* hfH, unsigned int* hfL, unsigned int* flags,
    const float* __restrict__ bfv, const float* __restrict__ biv,
    const float* __restrict__ bov, const float* __restrict__ bgv,
    float* __restrict__ out) {
  __shared__ unsigned short ldsU[2 * 32 * 512];  // 64 KB: U hi frags
  __shared__ float gbuf[2 * 8 * 32 * 32];        // 64 KB, XOR-swizzled
  __shared__ float hcell[32][17];

  const int wg = blockIdx.x;
  const int tid = threadIdx.x;
  const int lane = tid & 63;
  const int w = tid >> 6;

  {
    const bf16x8* src = reinterpret_cast<const bf16x8*>(ufragH + (size_t)wg * 32768);
    bf16x8* dst = reinterpret_cast<bf16x8*>(ldsU);
    for (int i = 0; i < 8; ++i) dst[i * 512 + tid] = src[i * 512 + tid];
  }
  __syncthreads();
  __builtin_amdgcn_fence(__ATOMIC_ACQUIRE, "agent");  // replay-stale L2 kill

  bf16x8 uL[2][4], vH[2][8], vL[2][8];
#pragma unroll
  for (int nt = 0; nt < 2; ++nt) {
    const bf16x8* bl = reinterpret_cast<const bf16x8*>(ufragL + (size_t)wg * 32768) +
                       (size_t)nt * 32 * 64;
#pragma unroll
    for (int p = 0; p < 4; ++p) uL[nt][p] = bl[(w * 4 + p) * 64 + lane];
    const bf16x8* vh =
        reinterpret_cast<const bf16x8*>(vfragH + (size_t)((wg * 2 + nt) * 64) * 512);
    const bf16x8* vl =
        reinterpret_cast<const bf16x8*>(vfragL + (size_t)((wg * 2 + nt) * 64) * 512);
#pragma unroll
    for (int q = 0; q < 8; ++q) {
      vH[nt][q] = vh[(w * 8 + q) * 64 + lane];
      vL[nt][q] = vl[(w * 8 + q) * 64 + lane];
    }
  }

  // cell-update ownership: 256 threads x 2 units (pair jp_)
  const int b_ = tid & 31;
  const int jp_ = (tid >> 5) & 7;
  const int jg0 = wg * 16 + 2 * jp_;
  const float Bf0 = bfv[jg0], Bf1 = bfv[jg0 + 1];
  const float Bi0 = biv[jg0], Bi1 = biv[jg0 + 1];
  const float Bo0 = bov[jg0], Bo1 = bov[jg0 + 1];
  const float Bg0 = bgv[jg0], Bg1 = bgv[jg0 + 1];
  float c0 = 0.f, c1 = 0.f;
  const int hw = wg * 256 + (b_ + 32 * (jp_ >> 2)) * 4 + (jp_ & 3);

#pragma unroll 1
  for (int t = 0; t < T_STEPS; ++t) {
    f32x16 acc0 = {};
    f32x16 acc1 = {};

    // ---- x@U hi+lo (no h dependency) ----
    {
      const bf16x8* axh = reinterpret_cast<const bf16x8*>(xfragH + (size_t)t * 16384);
      const bf16x8* axl = reinterpret_cast<const bf16x8*>(xfragL + (size_t)t * 16384);
      const bf16x8* lu = reinterpret_cast<const bf16x8*>(ldsU);
#pragma unroll
      for (int p = 0; p < 4; ++p) {
        int ktx = w * 4 + p;
        bf16x8 ah = axh[ktx * 64 + lane];
        bf16x8 al = axl[ktx * 64 + lane];
        bf16x8 u0 = lu[ktx * 64 + lane];
        bf16x8 u1 = lu[(32 + ktx) * 64 + lane];
        acc0 = __builtin_amdgcn_mfma_f32_32x32x16_bf16(ah, u0, acc0, 0, 0, 0);
        acc0 = __builtin_amdgcn_mfma_f32_32x32x16_bf16(ah, uL[0][p], acc0, 0, 0, 0);
        acc0 = __builtin_amdgcn_mfma_f32_32x32x16_bf16(al, u0, acc0, 0, 0, 0);
        acc1 = __builtin_amdgcn_mfma_f32_32x32x16_bf16(ah, u1, acc1, 0, 0, 0);
        acc1 = __builtin_amdgcn_mfma_f32_32x32x16_bf16(ah, uL[1][p], acc1, 0, 0, 0);
        acc1 = __builtin_amdgcn_mfma_f32_32x32x16_bf16(al, u1, acc1, 0, 0, 0);
      }
    }

    // ---- wait all h_{t-1}, then h@V ----
    if (t > 0) {
      if (tid < NWG) {
        while (__hip_atomic_load(&flags[tid], __ATOMIC_RELAXED,
                                 __HIP_MEMORY_SCOPE_AGENT) < (unsigned int)t) {
        }
      }
      __syncthreads();
      if (FULLSEQ) {
        // normal cached vector loads from the address-unique plane t-1
        const bf16x8* ahh = reinterpret_cast<const bf16x8*>(
            reinterpret_cast<const unsigned short*>(hfH) + (size_t)(t - 1) * 32768);
        const bf16x8* ahl = reinterpret_cast<const bf16x8*>(
            reinterpret_cast<const unsigned short*>(hfL) + (size_t)(t - 1) * 32768);
        bf16x8 aH[8], aL[8];
#pragma unroll
        for (int q = 0; q < 8; ++q) {
          aH[q] = ahh[(w * 8 + q) * 64 + lane];
          aL[q] = ahl[(w * 8 + q) * 64 + lane];
        }
#pragma unroll
        for (int q = 0; q < 8; ++q) {
          acc0 = __builtin_amdgcn_mfma_f32_32x32x16_bf16(aH[q], vH[0][q], acc0, 0, 0, 0);
          acc0 = __builtin_amdgcn_mfma_f32_32x32x16_bf16(aH[q], vL[0][q], acc0, 0, 0, 0);
          acc0 = __builtin_amdgcn_mfma_f32_32x32x16_bf16(aL[q], vH[0][q], acc0, 0, 0, 0);
          acc1 = __builtin_amdgcn_mfma_f32_32x32x16_bf16(aH[q], vH[1][q], acc1, 0, 0, 0);
          acc1 = __builtin_amdgcn_mfma_f32_32x32x16_bf16(aH[q], vL[1][q], acc1, 0, 0, 0);
          acc1 = __builtin_amdgcn_mfma_f32_32x32x16_bf16(aL[q], vH[1][q], acc1, 0, 0, 0);
        }
      } else {
        const unsigned int* hbH = hfH + (size_t)((t - 1) & 3) * 16384 + lane * 4;
        const unsigned int* hbL = hfL + (size_t)((t - 1) & 3) * 16384 + lane * 4;
        unsigned int rH[32], rL[32];
#pragma unroll
        for (int q = 0; q < 8; ++q)
#pragma unroll
          for (int d = 0; d < 4; ++d) {
            rH[q * 4 + d] = __hip_atomic_load(hbH + (w * 8 + q) * 256 + d,
                                              __ATOMIC_RELAXED,
                                              __HIP_MEMORY_SCOPE_AGENT);
            rL[q * 4 + d] = __hip_atomic_load(hbL + (w * 8 + q) * 256 + d,
                                              __ATOMIC_RELAXED,
                                              __HIP_MEMORY_SCOPE_AGENT);
          }
#pragma unroll
        for (int q = 0; q < 8; ++q) {
          union { unsigned int u[4]; bf16x8 v; } aH, aL;
#pragma unroll
          for (int d = 0; d < 4; ++d) {
            aH.u[d] = rH[q * 4 + d];
            aL.u[d] = rL[q * 4 + d];
          }
          acc0 = __builtin_amdgcn_mfma_f32_32x32x16_bf16(aH.v, vH[0][q], acc0, 0, 0, 0);
          acc0 = __builtin_amdgcn_mfma_f32_32x32x16_bf16(aH.v, vL[0][q], acc0, 0, 0, 0);
          acc0 = __builtin_amdgcn_mfma_f32_32x32x16_bf16(aL.v, vH[0][q], acc0, 0, 0, 0);
          acc1 = __builtin_amdgcn_mfma_f32_32x32x16_bf16(aH.v, vH[1][q], acc1, 0, 0, 0);
          acc1 = __builtin_amdgcn_mfma_f32_32x32x16_bf16(aH.v, vL[1][q], acc1, 0, 0, 0);
          acc1 = __builtin_amdgcn_mfma_f32_32x32x16_bf16(aL.v, vH[1][q], acc1, 0, 0, 0);
        }
      }
    }

    // ---- write partial C tiles (measured C/D layout), XOR-swizzled ----
    {
      const int colw = lane & 31;
      const int rbase = 4 * (lane >> 5);
#pragma unroll
      for (int r = 0; r < 16; ++r) {
        int row = (r & 3) + 8 * (r >> 2) + rbase;
        gbuf[gidx(0, w, row, colw)] = acc0[r];
        gbuf[gidx(1, w, row, colw)] = acc1[r];
      }
    }
    __syncthreads();

    // ---- cell update (256 thr x 2 units) + register publish ----
    if (tid < 256) {
      const int jl0 = 2 * jp_, jl1 = jl0 + 1;
      float gf0 = Bf0, gf1 = Bf1, gi0 = Bi0, gi1 = Bi1;
      float go0 = Bo0, go1 = Bo1, gg0 = Bg0, gg1 = Bg1;
#pragma unroll
      for (int ww = 0; ww < 8; ++ww) {
        gf0 += gbuf[gidx(0, ww, b_, jl0)];
        gf1 += gbuf[gidx(0, ww, b_, jl1)];
        gi0 += gbuf[gidx(0, ww, b_, 16 + jl0)];
        gi1 += gbuf[gidx(0, ww, b_, 16 + jl1)];
        go0 += gbuf[gidx(1, ww, b_, jl0)];
        go1 += gbuf[gidx(1, ww, b_, jl1)];
        gg0 += gbuf[gidx(1, ww, b_, 16 + jl0)];
        gg1 += gbuf[gidx(1, ww, b_, 16 + jl1)];
      }
      c0 = sigm(gf0) * c0 + sigm(gi0) * tanh_(gg0);
      c1 = sigm(gf1) * c1 + sigm(gi1) * tanh_(gg1);
      float h0 = sigm(go0) * tanh_(c0);
      float h1 = sigm(go1) * tanh_(c1);
      hcell[b_][jl0] = h0;
      hcell[b_][jl1] = h1;
      unsigned short h0h = f2bf(h0), h1h = f2bf(h1);
      unsigned short h0l = f2bf(h0 - b2f(h0h)), h1l = f2bf(h1 - b2f(h1h));
      unsigned int hvH = (unsigned int)h0h | ((unsigned int)h1h << 16);
      unsigned int hvL = (unsigned int)h0l | ((unsigned int)h1l << 16);
      size_t slotbase = FULLSEQ ? (size_t)t * 16384 : (size_t)(t & 3) * 16384;
      __hip_atomic_store(&hfH[slotbase + hw], hvH, __ATOMIC_RELAXED,
                         __HIP_MEMORY_SCOPE_AGENT);
      __hip_atomic_store(&hfL[slotbase + hw], hvL, __ATOMIC_RELAXED,
                         __HIP_MEMORY_SCOPE_AGENT);
    }
    __syncthreads();  // vmcnt(0): publishes completed at coherence point
    if (tid == 0) {
      __hip_atomic_store(&flags[wg], (unsigned int)(t + 1), __ATOMIC_RELAXED,
                         __HIP_MEMORY_SCOPE_AGENT);
    }
    // out stores AFTER the release (off the inter-WG critical path)
    {
      const int b2 = tid >> 4, jj = tid & 15;
      float hv = hcell[b2][jj];
      __builtin_nontemporal_store(
          hv, out + 32768 + ((size_t)(b2 * T_STEPS + t)) * HID + wg * 16 + jj);
      if (t == T_STEPS - 1)
        __builtin_nontemporal_store(hv, out + (size_t)b2 * HID + wg * 16 + jj);
    }
  }
}

// ================= r9 fallback (proven) =================
__global__ __launch_bounds__(256) void r9_step_gemm(
    const float* __restrict__ x, const float* __restrict__ hbuf,
    const float* __restrict__ Vf, const float* __restrict__ Vi,
    const float* __restrict__ Vo, const float* __restrict__ Vg,
    const float* __restrict__ Uf, const float* __restrict__ Ui,
    const float* __restrict__ Uo, const float* __restrict__ Ug,
    float* __restrict__ P, int t) {
  const int kb = blockIdx.x;
  const int cb = blockIdx.y;
  const int tidx = threadIdx.x;
  const int gate = cb >> 2;
  const int j = (cb & 3) * 256 + tidx;
  const int col = cb * 256 + tidx;
  const float* V_ = (gate == 0) ? Vf : (gate == 1) ? Vi : (gate == 2) ? Vo : Vg;
  const float* U_ = (gate == 0) ? Uf : (gate == 1) ? Ui : (gate == 2) ? Uo : Ug;
  __shared__ float hs[BS][32];
  __shared__ float xs2[BS][32];
  {
    int idx = tidx * 4;
#pragma unroll
    for (int i = 0; i < 4; ++i, ++idx) {
      int b = idx >> 5, u = idx & 31;
      hs[b][u] = hbuf[b * HID + kb * 32 + u];
      if (kb < 16) xs2[b][u] = x[((size_t)b * T_STEPS + t) * 512 + kb * 32 + u];
    }
  }
  __syncthreads();
  float acc[BS];
#pragma unroll
  for (int b = 0; b < BS; ++b) acc[b] = 0.f;
  const float* vp = V_ + (size_t)(kb * 32) * HID + j;
#pragma unroll 4
  for (int k = 0; k < 32; ++k) {
    float vv = vp[(size_t)k * HID];
#pragma unroll
    for (int b = 0; b < BS; ++b) acc[b] += hs[b][k] * vv;
  }
  if (kb < 16) {
    const float* up = U_ + (size_t)(kb * 32) * HID + j;
#pragma unroll 4
    for (int k = 0; k < 32; ++k) {
      float uv = up[(size_t)k * HID];
#pragma unroll
      for (int b = 0; b < BS; ++b) acc[b] += xs2[b][k] * uv;
    }
  }
  float* pp = P + (size_t)kb * BS * 4096 + col;
#pragma unroll
  for (int b = 0; b < BS; ++b) pp[(size_t)b * 4096] = acc[b];
}

__global__ __launch_bounds__(256) void r9_step_cell(
    const float* __restrict__ P,
    const float* __restrict__ bfv, const float* __restrict__ biv,
    const float* __restrict__ bov, const float* __restrict__ bgv,
    float* __restrict__ hbuf, float* __restrict__ cbuf,
    float* __restrict__ out, int t) {
  const int idx = blockIdx.x * 256 + threadIdx.x;
  const int b = idx >> 10, j = idx & 1023;
  float gf = bfv[j], gi = biv[j], go = bov[j], gg = bgv[j];
  const float* pb = P + (size_t)b * 4096;
#pragma unroll 8
  for (int kb = 0; kb < 32; ++kb) {
    const float* pk = pb + (size_t)kb * BS * 4096;
    gf += pk[j];
    gi += pk[1024 + j];
    go += pk[2048 + j];
    gg += pk[3072 + j];
  }
  float fs = sigm(gf), is = sigm(gi), os = sigm(go), gt = tanh_(gg);
  float c = fs * cbuf[idx] + is * gt;
  cbuf[idx] = c;
  float h = os * tanh_(c);
  hbuf[idx] = h;
  out[32768 + ((size_t)b * T_STEPS + t) * HID + j] = h;
  if (t == T_STEPS - 1) out[(size_t)b * HID + j] = h;
}

extern "C" void kernel_launch(void* const* d_in, const int* in_sizes, int n_in,
                              void* d_out, int out_size, void* d_ws, size_t ws_size,
                              hipStream_t stream) {
  const float *x, *Uf, *Vf, *bf, *Ui, *Vi, *bi, *Uo, *Vo, *bo, *Ug, *Vg, *bg;
  float* out = (float*)d_out;

  bool okA = (n_in == 13) && in_sizes[0] == 8388608 && in_sizes[1] == 524288 &&
             in_sizes[2] == 1048576 && in_sizes[3] == 1024 &&
             in_sizes[4] == 524288 && in_sizes[7] == 524288 &&
             in_sizes[10] == 524288 && in_sizes[12] == 1024;
  if (okA) {
    x = (const float*)d_in[0];
    Uf = (const float*)d_in[1];  Vf = (const float*)d_in[2];  bf = (const float*)d_in[3];
    Ui = (const float*)d_in[4];  Vi = (const float*)d_in[5];  bi = (const float*)d_in[6];
    Uo = (const float*)d_in[7];  Vo = (const float*)d_in[8];  bo = (const float*)d_in[9];
    Ug = (const float*)d_in[10]; Vg = (const float*)d_in[11]; bg = (const float*)d_in[12];
  } else {
    Uf = (const float*)d_in[0];  Ug = (const float*)d_in[1];
    Ui = (const float*)d_in[2];  Uo = (const float*)d_in[3];
    Vf = (const float*)d_in[4];  Vg = (const float*)d_in[5];
    Vi = (const float*)d_in[6];  Vo = (const float*)d_in[7];
    bf = (const float*)d_in[8];  bg = (const float*)d_in[9];
    bi = (const float*)d_in[10]; bo = (const float*)d_in[11];
    x = (const float*)d_in[12];
  }

  char* ws = (char*)d_ws;
  if (ws_size >= (size_t)WS_RING) {
    unsigned int* flags = (unsigned int*)(ws + 0);
    unsigned int* vfragH = (unsigned int*)(ws + 1048576);
    unsigned int* vfragL = (unsigned int*)(ws + 9437184);
    unsigned int* ufragH = (unsigned int*)(ws + 17825792);
    unsigned int* ufragL = (unsigned int*)(ws + 22020096);
    unsigned int* xfragH = (unsigned int*)(ws + 26214400);
    unsigned int* xfragL = (unsigned int*)(ws + 42991616);
    const bool full = ws_size >= (size_t)WS_FULL;
    // full-seq planes live past the frag area; ring reuses the low region
    unsigned int* hfH = (unsigned int*)(full ? ws + 59768832 : ws + 65536);
    unsigned int* hfL = (unsigned int*)(full ? ws + 93323264 : ws + 327680);

    (void)hipMemsetAsync(flags, 0, 4096, stream);
    cvt_uv_kernel<<<64 * 2 * 96, 64, 0, stream>>>(Uf, Vf, Ui, Vi, Uo, Vo, Ug, Vg,
                                                  vfragH, vfragL, ufragH, ufragL);
    cvt_x_kernel<<<512, 256, 0, stream>>>(x, xfragH, xfragL);
    if (full) {
      lstm_main<1><<<NWG, 512, 0, stream>>>(
          (unsigned short*)ufragH, (unsigned short*)ufragL, (unsigned short*)vfragH,
          (unsigned short*)vfragL, (unsigned short*)xfragH, (unsigned short*)xfragL,
          hfH, hfL, flags, bf, bi, bo, bg, out);
    } else {
      lstm_main<0><<<NWG, 512, 0, stream>>>(
          (unsigned short*)ufragH, (unsigned short*)ufragL, (unsigned short*)vfragH,
          (unsigned short*)vfragL, (unsigned short*)xfragH, (unsigned short*)xfragL,
          hfH, hfL, flags, bf, bi, bo, bg, out);
    }
  } else {
    float* P = (float*)ws;
    float* hbuf = (float*)(ws + 16777216);
    float* cbuf = (float*)(ws + 16908288);
    (void)hipMemsetAsync(hbuf, 0, 131072, stream);
    (void)hipMemsetAsync(cbuf, 0, 131072, stream);
    for (int t = 0; t < T_STEPS; ++t) {
      r9_step_gemm<<<dim3(32, 16), 256, 0, stream>>>(x, hbuf, Vf, Vi, Vo, Vg, Uf, Ui,
                                                     Uo, Ug, P, t);
      r9_step_cell<<<128, 256, 0, stream>>>(P, bf, bi, bo, bg, hbuf, cbuf, out, t);
    }
  }
}